// Round 7
// baseline (474.294 us; speedup 1.0000x reference)
//
#include <hip/hip_runtime.h>
#include <hip/hip_bf16.h>

#define B 16
#define L 64
#define P 1024
#define V 64
#define Q 16
#define LN64 4.158883083359672f

#define CHBC 16           // p per k_bc block
#define NCH_BC (P / CHBC) // 64

typedef unsigned short ushort8_t __attribute__((ext_vector_type(8)));

static __device__ __forceinline__ float bf2f(ushort u) {
    return __uint_as_float(((unsigned int)u) << 16);
}
static __device__ __forceinline__ ushort f2bf(float f) {
    unsigned int x = __float_as_uint(f);
    unsigned int r = (x + 0x7fffu + ((x >> 16) & 1u)) >> 16;
    return (ushort)r;
}
// packed bf16-pair helpers: word = bf16(lo) | bf16(hi)<<16
static __device__ __forceinline__ float pklo(unsigned int w) {
    return __uint_as_float(w << 16);
}
static __device__ __forceinline__ float pkhi(unsigned int w) {
    return __uint_as_float(w & 0xffff0000u);
}

static __device__ __forceinline__ float wsum64(float v) {
#pragma unroll
    for (int m = 32; m > 0; m >>= 1) v += __shfl_xor(v, m, 64);
    return v;
}
static __device__ __forceinline__ float wmax64(float v) {
#pragma unroll
    for (int m = 32; m > 0; m >>= 1) v = fmaxf(v, __shfl_xor(v, m, 64));
    return v;
}

// ---------------------------------------------------------------------------
// K_uhat v6: block = (p, l-half), 512 threads (8 waves). Wave w owns
// b in {2w, 2w+1}; lane = v. x packed as bf16 pairs in 16 VGPRs/thread
// (unpack = 1 bit-op per element; VALU has headroom). W 2-deep pipelined
// (32 VGPR). Total ~75 VGPR -> launch_bounds(512,6) = 24 waves/CU, so HBM
// latency is hidden by TLP (k_s evidence: 73% BW at high occupancy, no ILP).
// uhat layout [b][l][p][v].
// ---------------------------------------------------------------------------
__global__ __launch_bounds__(512, 6) void k_uhat(const float* __restrict__ Wt,
                                                 const float* __restrict__ x,
                                                 ushort* __restrict__ uhat) {
    const int t = threadIdx.x;
    const int w = t >> 6;          // b-pair index (0..7)
    const int lane = t & 63;       // v
    const int p = blockIdx.x >> 1;
    const int l0 = (blockIdx.x & 1) * 32;

    __shared__ float xs[B * Q];    // 1 KB
    if (t < B * Q) {
        const int b = t >> 4, q = t & 15;
        xs[t] = x[((size_t)b * P + p) * Q + q];
    }
    __syncthreads();

    // pack this wave's 2 b-rows of x as bf16 pairs: xp[i][j] = (q=2j | q=2j+1)
    unsigned int xp[2][8];
#pragma unroll
    for (int i = 0; i < 2; ++i) {
        const int b = w * 2 + i;
#pragma unroll
        for (int j = 0; j < 8; ++j) {
            unsigned int lo = f2bf(xs[b * Q + 2 * j]);
            unsigned int hi = f2bf(xs[b * Q + 2 * j + 1]);
            xp[i][j] = lo | (hi << 16);
        }
    }

    const float4* Wp0 = reinterpret_cast<const float4*>(Wt);

    float4 Wa[4], Wb[4];
#define LOADW(l, d)                                                          \
    {                                                                        \
        const float4* wp = Wp0 + (((size_t)(l) * P + p) * V + lane) * 4;     \
        d[0] = wp[0]; d[1] = wp[1]; d[2] = wp[2]; d[3] = wp[3];              \
    }
#define COMPUTE(l, Wr)                                                       \
    {                                                                        \
        _Pragma("unroll")                                                    \
        for (int i = 0; i < 2; ++i) {                                        \
            float u = 0.f;                                                   \
            _Pragma("unroll")                                                \
            for (int j = 0; j < 8; ++j) {                                    \
                const float wlo = (j & 1) ? ((j & 2) ? Wr[j >> 1].z          \
                                                     : Wr[j >> 1].z)         \
                                          : Wr[j >> 1].x;                    \
                const float whi = (j & 1) ? Wr[j >> 1].w : Wr[j >> 1].y;     \
                u = fmaf(wlo, pklo(xp[i][j]), u);                            \
                u = fmaf(whi, pkhi(xp[i][j]), u);                            \
            }                                                                \
            const int b = w * 2 + i;                                         \
            uhat[(((size_t)(b * L + (l))) * P + p) * V + lane] = f2bf(u);    \
        }                                                                    \
    }

    LOADW(l0 + 0, Wa);
#pragma unroll 2
    for (int li = 0; li < 32; li += 2) {
        LOADW(l0 + li + 1, Wb);
        COMPUTE(l0 + li, Wa);
        if (li + 2 < 32) LOADW(l0 + li + 2, Wa);
        COMPUTE(l0 + li + 1, Wb);
    }
#undef LOADW
#undef COMPUTE
}

// ---------------------------------------------------------------------------
// K_s: per (b,l) block, iter-0 only (uniform c). s[v] = (1/64) sum_p u[p,v],
// fused squash. Thread t owns (pl = t>>4, v0 = (t&15)*4); ushort4 loads.
// ---------------------------------------------------------------------------
__global__ __launch_bounds__(256) void k_s(const ushort* __restrict__ uhat,
                                           float* __restrict__ vout) {
    const int l = blockIdx.x, b = blockIdx.y;
    const int t = threadIdx.x;
    const int w = t >> 6, lane = t & 63;
    const int pl = t >> 4;      // 0..15
    const int vg = t & 15;      // v0 = vg*4

    __shared__ float4 sl[4][16];

    const ushort* up = uhat + ((size_t)(b * L + l)) * P * V + (size_t)pl * V + vg * 4;

    float4 acc = {0.f, 0.f, 0.f, 0.f};
#pragma unroll 8
    for (int i = 0; i < 64; ++i) {
        ushort4 u = *reinterpret_cast<const ushort4*>(up + (size_t)i * 16 * V);
        acc.x += bf2f(u.x); acc.y += bf2f(u.y);
        acc.z += bf2f(u.z); acc.w += bf2f(u.w);
    }
    acc.x *= (1.f / 64.f); acc.y *= (1.f / 64.f);
    acc.z *= (1.f / 64.f); acc.w *= (1.f / 64.f);
#pragma unroll
    for (int m = 16; m <= 32; m <<= 1) {
        acc.x += __shfl_xor(acc.x, m, 64);
        acc.y += __shfl_xor(acc.y, m, 64);
        acc.z += __shfl_xor(acc.z, m, 64);
        acc.w += __shfl_xor(acc.w, m, 64);
    }
    if (lane < 16) sl[w][vg] = acc;
    __syncthreads();
    if (w == 0 && lane < 16) {
        float4 s0 = sl[0][vg], s1 = sl[1][vg], s2 = sl[2][vg], s3 = sl[3][vg];
        float4 s;
        s.x = s0.x + s1.x + s2.x + s3.x;
        s.y = s0.y + s1.y + s2.y + s3.y;
        s.z = s0.z + s1.z + s2.z + s3.z;
        s.w = s0.w + s1.w + s2.w + s3.w;
        float sq = s.x * s.x + s.y * s.y + s.z * s.z + s.w * s.w;
        sq += __shfl_xor(sq, 1, 64);
        sq += __shfl_xor(sq, 2, 64);
        sq += __shfl_xor(sq, 4, 64);
        sq += __shfl_xor(sq, 8, 64);
        float f = sqrtf(sq) / (1.0f + sq);
        float4 o = {s.x * f, s.y * f, s.z * f, s.w * f};
        *reinterpret_cast<float4*>(vout + (size_t)(b * L + l) * V + vg * 4) = o;
    }
}

// ---------------------------------------------------------------------------
// K_bc v6: block = (ch of 16 p, b), 512 threads (8 waves). u tile kept in
// REGISTERS (ur[8][2] ushort8 per thread = 64 VGPR); LDS only vsh+bl (20 KB)
// -> 2 blocks/CU. lane = (pl8 = p, vg8 = v-octet); wave w owns l in [8w,8w+8).
// phase 1: issue all 16 coalesced 1KB u-loads, dot with v -> bl[p][l].
// phase 2: softmax over l per p (each wave 2 p's); b-logit update; optional T.
// phase 3: s-partial from registers, butterfly over pl8 -> sp[b][ch][l][v].
// u_hat crosses HBM exactly once per launch.
// ---------------------------------------------------------------------------
__global__ __launch_bounds__(512, 4) void k_bc(const ushort* __restrict__ uhat,
                                               const float* __restrict__ vv,
                                               float* __restrict__ bbuf,
                                               float* __restrict__ sp,
                                               float* __restrict__ Tsum,
                                               int add_prev, int do_T) {
    const int ch = blockIdx.x, b = blockIdx.y;
    const int p0 = ch * CHBC;
    const int t = threadIdx.x;
    const int w = t >> 6, lane = t & 63;
    const int pl8 = lane >> 3;   // p-local (phase 0 of 8)
    const int vg8 = lane & 7;    // v-octet
    const int l0 = w * 8;

    __shared__ float vsh[L][V];         // 16 KB
    __shared__ float bl[CHBC][L + 1];   // 4.06 KB (logits, then c in place)
    __shared__ float twv[8];

    // stage v[b,:,:] (ds_writes complete at the barrier)
    {
        const float4* vvp = reinterpret_cast<const float4*>(vv + (size_t)b * L * V);
        float4* vshp = reinterpret_cast<float4*>(&vsh[0][0]);
#pragma unroll
        for (int i = 0; i < 2; ++i) vshp[t + i * 512] = vvp[t + i * 512];
    }

    // issue ALL u loads before the barrier (latency overlaps the v-stage)
    ushort8_t ur[8][2];
    {
        const ushort* ubase = uhat + (((size_t)(b * L + l0)) * P + p0 + pl8) * V + vg8 * 8;
#pragma unroll
        for (int li = 0; li < 8; ++li) {
#pragma unroll
            for (int ph = 0; ph < 2; ++ph)
                ur[li][ph] = *reinterpret_cast<const ushort8_t*>(
                    ubase + ((size_t)li * P + ph * 8) * V);
        }
    }
    __syncthreads();

    // phase 1: dot with v; 3-shfl reduce over vg8 -> bl[p][l]
#pragma unroll
    for (int li = 0; li < 8; ++li) {
        const int l = l0 + li;
        const float4 va = *reinterpret_cast<const float4*>(&vsh[l][vg8 * 8]);
        const float4 vb = *reinterpret_cast<const float4*>(&vsh[l][vg8 * 8 + 4]);
#pragma unroll
        for (int ph = 0; ph < 2; ++ph) {
            float d;
            d = bf2f(ur[li][ph][0]) * va.x;
            d = fmaf(bf2f(ur[li][ph][1]), va.y, d);
            d = fmaf(bf2f(ur[li][ph][2]), va.z, d);
            d = fmaf(bf2f(ur[li][ph][3]), va.w, d);
            d = fmaf(bf2f(ur[li][ph][4]), vb.x, d);
            d = fmaf(bf2f(ur[li][ph][5]), vb.y, d);
            d = fmaf(bf2f(ur[li][ph][6]), vb.z, d);
            d = fmaf(bf2f(ur[li][ph][7]), vb.w, d);
            d += __shfl_xor(d, 1, 64);
            d += __shfl_xor(d, 2, 64);
            d += __shfl_xor(d, 4, 64);
            if (vg8 == 0) bl[ph * 8 + pl8][l] = d;
        }
    }
    __syncthreads();

    // phase 2: each wave softmaxes 2 p's (lane = l); c overwrites bl
    float tloc = 0.f;
#pragma unroll
    for (int pi = 0; pi < 2; ++pi) {
        const int pli = w * 2 + pi;
        const int p = p0 + pli;
        float bv = bl[pli][lane];
        float* bp = bbuf + ((size_t)b * P + p) * L;
        if (add_prev) bv += bp[lane];
        bp[lane] = bv;
        float m = wmax64(bv);
        float e = __expf(bv - m);
        float ssum = wsum64(e);
        float cc = e / ssum;
        bl[pli][lane] = cc;
        if (do_T) tloc += cc * __logf(64.0f * (cc + 1e-12f));
    }
    if (do_T) {
        float dsum = wsum64(tloc);
        if (lane == 0) twv[w] = dsum;
    }
    __syncthreads();
    if (do_T && t == 0) {
        float s8 = twv[0] + twv[1] + twv[2] + twv[3] +
                   twv[4] + twv[5] + twv[6] + twv[7];
        atomicAdd(Tsum, s8 * (1.0f / LN64));
    }

    // phase 3: s-partial from registers; butterfly over pl8 (lane bits 3..5)
    float* spb = sp + (size_t)(b * NCH_BC + ch) * L * V;
#pragma unroll
    for (int li = 0; li < 8; ++li) {
        const int l = l0 + li;
        const float cA = bl[pl8][l];        // p = p0 + pl8
        const float cB = bl[8 + pl8][l];    // p = p0 + 8 + pl8
        float4 pa, pb;
        pa.x = cA * bf2f(ur[li][0][0]) + cB * bf2f(ur[li][1][0]);
        pa.y = cA * bf2f(ur[li][0][1]) + cB * bf2f(ur[li][1][1]);
        pa.z = cA * bf2f(ur[li][0][2]) + cB * bf2f(ur[li][1][2]);
        pa.w = cA * bf2f(ur[li][0][3]) + cB * bf2f(ur[li][1][3]);
        pb.x = cA * bf2f(ur[li][0][4]) + cB * bf2f(ur[li][1][4]);
        pb.y = cA * bf2f(ur[li][0][5]) + cB * bf2f(ur[li][1][5]);
        pb.z = cA * bf2f(ur[li][0][6]) + cB * bf2f(ur[li][1][6]);
        pb.w = cA * bf2f(ur[li][0][7]) + cB * bf2f(ur[li][1][7]);
#pragma unroll
        for (int m = 8; m <= 32; m <<= 1) {
            pa.x += __shfl_xor(pa.x, m, 64);
            pa.y += __shfl_xor(pa.y, m, 64);
            pa.z += __shfl_xor(pa.z, m, 64);
            pa.w += __shfl_xor(pa.w, m, 64);
            pb.x += __shfl_xor(pb.x, m, 64);
            pb.y += __shfl_xor(pb.y, m, 64);
            pb.z += __shfl_xor(pb.z, m, 64);
            pb.w += __shfl_xor(pb.w, m, 64);
        }
        if (pl8 == 0) {
            *reinterpret_cast<float4*>(spb + (size_t)l * V + vg8 * 8) = pa;
            *reinterpret_cast<float4*>(spb + (size_t)l * V + vg8 * 8 + 4) = pb;
        }
    }
}

// ---------------------------------------------------------------------------
// K_v: chunk-reduce + squash. sp[b][ch][l][v]. grid (L/4, B); wave w -> l.
// ---------------------------------------------------------------------------
__global__ __launch_bounds__(256) void k_v(const float* __restrict__ sp,
                                           float* __restrict__ vout,
                                           float* __restrict__ norms) {
    const int b = blockIdx.y;
    const int w = threadIdx.x >> 6, lane = threadIdx.x & 63;
    const int l = blockIdx.x * 4 + w;
    const float* p = sp + ((size_t)b * NCH_BC * L + l) * V + lane;
    float s = 0.f;
#pragma unroll 8
    for (int ch = 0; ch < NCH_BC; ++ch) s += p[(size_t)ch * L * V];
    float sq = wsum64(s * s);
    float f = sqrtf(sq) / (1.0f + sq);
    vout[((size_t)b * L + l) * V + lane] = s * f;
    if (norms && lane == 0) norms[b * L + l] = sq / (1.0f + sq);
}

// ---------------------------------------------------------------------------
// K_final: T and D. One block, 64 threads (lane = l).
// ---------------------------------------------------------------------------
__global__ void k_final(const float* __restrict__ Tsum,
                        const float* __restrict__ norms,
                        float* __restrict__ out) {
    const int lane = threadIdx.x & 63;
    float n[B];
    float sum = 0.f;
#pragma unroll
    for (int b = 0; b < B; ++b) { n[b] = norms[b * L + lane]; sum += n[b]; }
    const float mean = sum * (1.0f / B);
    float var = 0.f;
#pragma unroll
    for (int b = 0; b < B; ++b) { float d = n[b] - mean; var = fmaf(d, d, var); }
    var *= (1.0f / B);
    float sd = sqrtf(var);
    float D = wmax64(sd);
    if (lane == 0) {
        out[B * L * V] = Tsum[0] * (1.0f / (B * P));
        out[B * L * V + 1] = D;
    }
}

extern "C" void kernel_launch(void* const* d_in, const int* in_sizes, int n_in,
                              void* d_out, int out_size, void* d_ws, size_t ws_size,
                              hipStream_t stream) {
    const float* x = (const float*)d_in[0];   // (B,P,Q)
    const float* W = (const float*)d_in[1];   // (L,P,V,Q)
    float* out = (float*)d_out;               // v (B,L,V) then T, D

    char* ws = (char*)d_ws;
    ushort* uhat = (ushort*)ws;                        // [b][l][p][v] bf16 = 128 MB
    size_t off = (size_t)B * L * P * V * 2;
    float* spbuf = (float*)(ws + off); off += (size_t)B * NCH_BC * L * V * 4;  // 16 MB
    float* vbuf  = (float*)(ws + off); off += (size_t)B * L * V * 4;
    float* bbuf  = (float*)(ws + off); off += (size_t)B * P * L * 4;           // 4 MB [b][p][l]
    float* norms = (float*)(ws + off); off += (size_t)B * L * 4;
    float* Tsum  = (float*)(ws + off); off += 256;

    hipMemsetAsync(Tsum, 0, sizeof(float), stream);

    // u_hat
    hipLaunchKernelGGL(k_uhat, dim3(2048), dim3(512), 0, stream, W, x, uhat);
    // iter 0: uniform c -> v0
    hipLaunchKernelGGL(k_s, dim3(L, B), dim3(256), 0, stream, uhat, vbuf);
    // b1 = v0.u ; c1 ; partial s1 (fused, u in registers)
    hipLaunchKernelGGL(k_bc, dim3(NCH_BC, B), dim3(512), 0, stream,
                       uhat, vbuf, bbuf, spbuf, Tsum, 0, 0);
    // v1
    hipLaunchKernelGGL(k_v, dim3(L / 4, B), dim3(256), 0, stream,
                       spbuf, vbuf, (float*)nullptr);
    // b2 = b1 + v1.u ; c2 ; T partials ; partial s2
    hipLaunchKernelGGL(k_bc, dim3(NCH_BC, B), dim3(512), 0, stream,
                       uhat, vbuf, bbuf, spbuf, Tsum, 1, 1);
    // v2 -> out, norms
    hipLaunchKernelGGL(k_v, dim3(L / 4, B), dim3(256), 0, stream,
                       spbuf, out, norms);
    hipLaunchKernelGGL(k_final, dim3(1), dim3(64), 0, stream, Tsum, norms, out);
}

// Round 8
// 357.277 us; speedup vs baseline: 1.3275x; 1.3275x over previous
//
#include <hip/hip_runtime.h>
#include <hip/hip_bf16.h>

#define B 16
#define L 64
#define P 1024
#define V 64
#define Q 16
#define LN64 4.158883083359672f

#define CHBC 16           // p per k_bc block
#define NCH_BC (P / CHBC) // 64

typedef unsigned short ushort8_t __attribute__((ext_vector_type(8)));

static __device__ __forceinline__ float bf2f(ushort u) {
    return __uint_as_float(((unsigned int)u) << 16);
}
static __device__ __forceinline__ ushort f2bf(float f) {
    unsigned int x = __float_as_uint(f);
    unsigned int r = (x + 0x7fffu + ((x >> 16) & 1u)) >> 16;
    return (ushort)r;
}
// packed bf16-pair helpers: word = bf16(lo) | bf16(hi)<<16
static __device__ __forceinline__ float pklo(unsigned int w) {
    return __uint_as_float(w << 16);
}
static __device__ __forceinline__ float pkhi(unsigned int w) {
    return __uint_as_float(w & 0xffff0000u);
}

static __device__ __forceinline__ float wsum64(float v) {
#pragma unroll
    for (int m = 32; m > 0; m >>= 1) v += __shfl_xor(v, m, 64);
    return v;
}
static __device__ __forceinline__ float wmax64(float v) {
#pragma unroll
    for (int m = 32; m > 0; m >>= 1) v = fmaxf(v, __shfl_xor(v, m, 64));
    return v;
}

// ---------------------------------------------------------------------------
// K_uhat v7: block = (p, l-half), 512 threads (8 waves). Wave w owns
// b in {2w, 2w+1}; lane = v. x packed as bf16 pairs in 16 VGPRs/thread.
// W 2-deep pipelined (32 VGPR). launch_bounds(512,4): VGPR cap 128 -- ABOVE
// natural ~90 usage (round-7 lesson: cap 40 caused scratch spill, 971 MB
// traffic). 4 waves/SIMD for TLP latency hiding. uhat layout [b][l][p][v].
// ---------------------------------------------------------------------------
__global__ __launch_bounds__(512, 4) void k_uhat(const float* __restrict__ Wt,
                                                 const float* __restrict__ x,
                                                 ushort* __restrict__ uhat) {
    const int t = threadIdx.x;
    const int w = t >> 6;          // b-pair index (0..7)
    const int lane = t & 63;       // v
    const int p = blockIdx.x >> 1;
    const int l0 = (blockIdx.x & 1) * 32;

    __shared__ float xs[B * Q];    // 1 KB
    if (t < B * Q) {
        const int b = t >> 4, q = t & 15;
        xs[t] = x[((size_t)b * P + p) * Q + q];
    }
    __syncthreads();

    // pack this wave's 2 b-rows of x as bf16 pairs: xp[i][j] = (q=2j | q=2j+1)
    unsigned int xp[2][8];
#pragma unroll
    for (int i = 0; i < 2; ++i) {
        const int b = w * 2 + i;
#pragma unroll
        for (int j = 0; j < 8; ++j) {
            unsigned int lo = f2bf(xs[b * Q + 2 * j]);
            unsigned int hi = f2bf(xs[b * Q + 2 * j + 1]);
            xp[i][j] = lo | (hi << 16);
        }
    }

    const float4* Wp0 = reinterpret_cast<const float4*>(Wt);

    float4 Wa[4], Wb[4];
#define LOADW(l, d)                                                          \
    {                                                                        \
        const float4* wp = Wp0 + (((size_t)(l) * P + p) * V + lane) * 4;     \
        d[0] = wp[0]; d[1] = wp[1]; d[2] = wp[2]; d[3] = wp[3];              \
    }
#define COMPUTE(l, Wr)                                                       \
    {                                                                        \
        _Pragma("unroll")                                                    \
        for (int i = 0; i < 2; ++i) {                                        \
            float u = 0.f;                                                   \
            _Pragma("unroll")                                                \
            for (int j = 0; j < 8; ++j) {                                    \
                const float wlo = (j & 1) ? Wr[j >> 1].z : Wr[j >> 1].x;     \
                const float whi = (j & 1) ? Wr[j >> 1].w : Wr[j >> 1].y;     \
                u = fmaf(wlo, pklo(xp[i][j]), u);                            \
                u = fmaf(whi, pkhi(xp[i][j]), u);                            \
            }                                                                \
            const int b = w * 2 + i;                                         \
            uhat[(((size_t)(b * L + (l))) * P + p) * V + lane] = f2bf(u);    \
        }                                                                    \
    }

    LOADW(l0 + 0, Wa);
#pragma unroll 2
    for (int li = 0; li < 32; li += 2) {
        LOADW(l0 + li + 1, Wb);
        COMPUTE(l0 + li, Wa);
        if (li + 2 < 32) LOADW(l0 + li + 2, Wa);
        COMPUTE(l0 + li + 1, Wb);
    }
#undef LOADW
#undef COMPUTE
}

// ---------------------------------------------------------------------------
// K_s: per (b,l) block, iter-0 only (uniform c). s[v] = (1/64) sum_p u[p,v],
// fused squash. Thread t owns (pl = t>>4, v0 = (t&15)*4); ushort4 loads.
// ---------------------------------------------------------------------------
__global__ __launch_bounds__(256) void k_s(const ushort* __restrict__ uhat,
                                           float* __restrict__ vout) {
    const int l = blockIdx.x, b = blockIdx.y;
    const int t = threadIdx.x;
    const int w = t >> 6, lane = t & 63;
    const int pl = t >> 4;      // 0..15
    const int vg = t & 15;      // v0 = vg*4

    __shared__ float4 sl[4][16];

    const ushort* up = uhat + ((size_t)(b * L + l)) * P * V + (size_t)pl * V + vg * 4;

    float4 acc = {0.f, 0.f, 0.f, 0.f};
#pragma unroll 8
    for (int i = 0; i < 64; ++i) {
        ushort4 u = *reinterpret_cast<const ushort4*>(up + (size_t)i * 16 * V);
        acc.x += bf2f(u.x); acc.y += bf2f(u.y);
        acc.z += bf2f(u.z); acc.w += bf2f(u.w);
    }
    acc.x *= (1.f / 64.f); acc.y *= (1.f / 64.f);
    acc.z *= (1.f / 64.f); acc.w *= (1.f / 64.f);
#pragma unroll
    for (int m = 16; m <= 32; m <<= 1) {
        acc.x += __shfl_xor(acc.x, m, 64);
        acc.y += __shfl_xor(acc.y, m, 64);
        acc.z += __shfl_xor(acc.z, m, 64);
        acc.w += __shfl_xor(acc.w, m, 64);
    }
    if (lane < 16) sl[w][vg] = acc;
    __syncthreads();
    if (w == 0 && lane < 16) {
        float4 s0 = sl[0][vg], s1 = sl[1][vg], s2 = sl[2][vg], s3 = sl[3][vg];
        float4 s;
        s.x = s0.x + s1.x + s2.x + s3.x;
        s.y = s0.y + s1.y + s2.y + s3.y;
        s.z = s0.z + s1.z + s2.z + s3.z;
        s.w = s0.w + s1.w + s2.w + s3.w;
        float sq = s.x * s.x + s.y * s.y + s.z * s.z + s.w * s.w;
        sq += __shfl_xor(sq, 1, 64);
        sq += __shfl_xor(sq, 2, 64);
        sq += __shfl_xor(sq, 4, 64);
        sq += __shfl_xor(sq, 8, 64);
        float f = sqrtf(sq) / (1.0f + sq);
        float4 o = {s.x * f, s.y * f, s.z * f, s.w * f};
        *reinterpret_cast<float4*>(vout + (size_t)(b * L + l) * V + vg * 4) = o;
    }
}

// ---------------------------------------------------------------------------
// K_bc v6: block = (ch of 16 p, b), 512 threads (8 waves). u tile kept in
// REGISTERS (ur[8][2] ushort8 per thread = 64 VGPR); LDS only vsh+bl (20 KB)
// -> 2 blocks/CU. lane = (pl8 = p, vg8 = v-octet); wave w owns l in [8w,8w+8).
// phase 1: issue all 16 coalesced 1KB u-loads, dot with v -> bl[p][l].
// phase 2: softmax over l per p (each wave 2 p's); b-logit update; optional T.
// phase 3: s-partial from registers, butterfly over pl8 -> sp[b][ch][l][v].
// u_hat crosses HBM exactly once per launch.
// ---------------------------------------------------------------------------
__global__ __launch_bounds__(512, 4) void k_bc(const ushort* __restrict__ uhat,
                                               const float* __restrict__ vv,
                                               float* __restrict__ bbuf,
                                               float* __restrict__ sp,
                                               float* __restrict__ Tsum,
                                               int add_prev, int do_T) {
    const int ch = blockIdx.x, b = blockIdx.y;
    const int p0 = ch * CHBC;
    const int t = threadIdx.x;
    const int w = t >> 6, lane = t & 63;
    const int pl8 = lane >> 3;   // p-local (phase 0 of 8)
    const int vg8 = lane & 7;    // v-octet
    const int l0 = w * 8;

    __shared__ float vsh[L][V];         // 16 KB
    __shared__ float bl[CHBC][L + 1];   // 4.06 KB (logits, then c in place)
    __shared__ float twv[8];

    // stage v[b,:,:] (ds_writes complete at the barrier)
    {
        const float4* vvp = reinterpret_cast<const float4*>(vv + (size_t)b * L * V);
        float4* vshp = reinterpret_cast<float4*>(&vsh[0][0]);
#pragma unroll
        for (int i = 0; i < 2; ++i) vshp[t + i * 512] = vvp[t + i * 512];
    }

    // issue ALL u loads before the barrier (latency overlaps the v-stage)
    ushort8_t ur[8][2];
    {
        const ushort* ubase = uhat + (((size_t)(b * L + l0)) * P + p0 + pl8) * V + vg8 * 8;
#pragma unroll
        for (int li = 0; li < 8; ++li) {
#pragma unroll
            for (int ph = 0; ph < 2; ++ph)
                ur[li][ph] = *reinterpret_cast<const ushort8_t*>(
                    ubase + ((size_t)li * P + ph * 8) * V);
        }
    }
    __syncthreads();

    // phase 1: dot with v; 3-shfl reduce over vg8 -> bl[p][l]
#pragma unroll
    for (int li = 0; li < 8; ++li) {
        const int l = l0 + li;
        const float4 va = *reinterpret_cast<const float4*>(&vsh[l][vg8 * 8]);
        const float4 vb = *reinterpret_cast<const float4*>(&vsh[l][vg8 * 8 + 4]);
#pragma unroll
        for (int ph = 0; ph < 2; ++ph) {
            float d;
            d = bf2f(ur[li][ph][0]) * va.x;
            d = fmaf(bf2f(ur[li][ph][1]), va.y, d);
            d = fmaf(bf2f(ur[li][ph][2]), va.z, d);
            d = fmaf(bf2f(ur[li][ph][3]), va.w, d);
            d = fmaf(bf2f(ur[li][ph][4]), vb.x, d);
            d = fmaf(bf2f(ur[li][ph][5]), vb.y, d);
            d = fmaf(bf2f(ur[li][ph][6]), vb.z, d);
            d = fmaf(bf2f(ur[li][ph][7]), vb.w, d);
            d += __shfl_xor(d, 1, 64);
            d += __shfl_xor(d, 2, 64);
            d += __shfl_xor(d, 4, 64);
            if (vg8 == 0) bl[ph * 8 + pl8][l] = d;
        }
    }
    __syncthreads();

    // phase 2: each wave softmaxes 2 p's (lane = l); c overwrites bl
    float tloc = 0.f;
#pragma unroll
    for (int pi = 0; pi < 2; ++pi) {
        const int pli = w * 2 + pi;
        const int p = p0 + pli;
        float bv = bl[pli][lane];
        float* bp = bbuf + ((size_t)b * P + p) * L;
        if (add_prev) bv += bp[lane];
        bp[lane] = bv;
        float m = wmax64(bv);
        float e = __expf(bv - m);
        float ssum = wsum64(e);
        float cc = e / ssum;
        bl[pli][lane] = cc;
        if (do_T) tloc += cc * __logf(64.0f * (cc + 1e-12f));
    }
    if (do_T) {
        float dsum = wsum64(tloc);
        if (lane == 0) twv[w] = dsum;
    }
    __syncthreads();
    if (do_T && t == 0) {
        float s8 = twv[0] + twv[1] + twv[2] + twv[3] +
                   twv[4] + twv[5] + twv[6] + twv[7];
        atomicAdd(Tsum, s8 * (1.0f / LN64));
    }

    // phase 3: s-partial from registers; butterfly over pl8 (lane bits 3..5)
    float* spb = sp + (size_t)(b * NCH_BC + ch) * L * V;
#pragma unroll
    for (int li = 0; li < 8; ++li) {
        const int l = l0 + li;
        const float cA = bl[pl8][l];        // p = p0 + pl8
        const float cB = bl[8 + pl8][l];    // p = p0 + 8 + pl8
        float4 pa, pb;
        pa.x = cA * bf2f(ur[li][0][0]) + cB * bf2f(ur[li][1][0]);
        pa.y = cA * bf2f(ur[li][0][1]) + cB * bf2f(ur[li][1][1]);
        pa.z = cA * bf2f(ur[li][0][2]) + cB * bf2f(ur[li][1][2]);
        pa.w = cA * bf2f(ur[li][0][3]) + cB * bf2f(ur[li][1][3]);
        pb.x = cA * bf2f(ur[li][0][4]) + cB * bf2f(ur[li][1][4]);
        pb.y = cA * bf2f(ur[li][0][5]) + cB * bf2f(ur[li][1][5]);
        pb.z = cA * bf2f(ur[li][0][6]) + cB * bf2f(ur[li][1][6]);
        pb.w = cA * bf2f(ur[li][0][7]) + cB * bf2f(ur[li][1][7]);
#pragma unroll
        for (int m = 8; m <= 32; m <<= 1) {
            pa.x += __shfl_xor(pa.x, m, 64);
            pa.y += __shfl_xor(pa.y, m, 64);
            pa.z += __shfl_xor(pa.z, m, 64);
            pa.w += __shfl_xor(pa.w, m, 64);
            pb.x += __shfl_xor(pb.x, m, 64);
            pb.y += __shfl_xor(pb.y, m, 64);
            pb.z += __shfl_xor(pb.z, m, 64);
            pb.w += __shfl_xor(pb.w, m, 64);
        }
        if (pl8 == 0) {
            *reinterpret_cast<float4*>(spb + (size_t)l * V + vg8 * 8) = pa;
            *reinterpret_cast<float4*>(spb + (size_t)l * V + vg8 * 8 + 4) = pb;
        }
    }
}

// ---------------------------------------------------------------------------
// K_v: chunk-reduce + squash. sp[b][ch][l][v]. grid (L/4, B); wave w -> l.
// ---------------------------------------------------------------------------
__global__ __launch_bounds__(256) void k_v(const float* __restrict__ sp,
                                           float* __restrict__ vout,
                                           float* __restrict__ norms) {
    const int b = blockIdx.y;
    const int w = threadIdx.x >> 6, lane = threadIdx.x & 63;
    const int l = blockIdx.x * 4 + w;
    const float* p = sp + ((size_t)b * NCH_BC * L + l) * V + lane;
    float s = 0.f;
#pragma unroll 8
    for (int ch = 0; ch < NCH_BC; ++ch) s += p[(size_t)ch * L * V];
    float sq = wsum64(s * s);
    float f = sqrtf(sq) / (1.0f + sq);
    vout[((size_t)b * L + l) * V + lane] = s * f;
    if (norms && lane == 0) norms[b * L + l] = sq / (1.0f + sq);
}

// ---------------------------------------------------------------------------
// K_final: T and D. One block, 64 threads (lane = l).
// ---------------------------------------------------------------------------
__global__ void k_final(const float* __restrict__ Tsum,
                        const float* __restrict__ norms,
                        float* __restrict__ out) {
    const int lane = threadIdx.x & 63;
    float n[B];
    float sum = 0.f;
#pragma unroll
    for (int b = 0; b < B; ++b) { n[b] = norms[b * L + lane]; sum += n[b]; }
    const float mean = sum * (1.0f / B);
    float var = 0.f;
#pragma unroll
    for (int b = 0; b < B; ++b) { float d = n[b] - mean; var = fmaf(d, d, var); }
    var *= (1.0f / B);
    float sd = sqrtf(var);
    float D = wmax64(sd);
    if (lane == 0) {
        out[B * L * V] = Tsum[0] * (1.0f / (B * P));
        out[B * L * V + 1] = D;
    }
}

extern "C" void kernel_launch(void* const* d_in, const int* in_sizes, int n_in,
                              void* d_out, int out_size, void* d_ws, size_t ws_size,
                              hipStream_t stream) {
    const float* x = (const float*)d_in[0];   // (B,P,Q)
    const float* W = (const float*)d_in[1];   // (L,P,V,Q)
    float* out = (float*)d_out;               // v (B,L,V) then T, D

    char* ws = (char*)d_ws;
    ushort* uhat = (ushort*)ws;                        // [b][l][p][v] bf16 = 128 MB
    size_t off = (size_t)B * L * P * V * 2;
    float* spbuf = (float*)(ws + off); off += (size_t)B * NCH_BC * L * V * 4;  // 16 MB
    float* vbuf  = (float*)(ws + off); off += (size_t)B * L * V * 4;
    float* bbuf  = (float*)(ws + off); off += (size_t)B * P * L * 4;           // 4 MB [b][p][l]
    float* norms = (float*)(ws + off); off += (size_t)B * L * 4;
    float* Tsum  = (float*)(ws + off); off += 256;

    hipMemsetAsync(Tsum, 0, sizeof(float), stream);

    // u_hat
    hipLaunchKernelGGL(k_uhat, dim3(2048), dim3(512), 0, stream, W, x, uhat);
    // iter 0: uniform c -> v0
    hipLaunchKernelGGL(k_s, dim3(L, B), dim3(256), 0, stream, uhat, vbuf);
    // b1 = v0.u ; c1 ; partial s1 (fused, u in registers)
    hipLaunchKernelGGL(k_bc, dim3(NCH_BC, B), dim3(512), 0, stream,
                       uhat, vbuf, bbuf, spbuf, Tsum, 0, 0);
    // v1
    hipLaunchKernelGGL(k_v, dim3(L / 4, B), dim3(256), 0, stream,
                       spbuf, vbuf, (float*)nullptr);
    // b2 = b1 + v1.u ; c2 ; T partials ; partial s2
    hipLaunchKernelGGL(k_bc, dim3(NCH_BC, B), dim3(512), 0, stream,
                       uhat, vbuf, bbuf, spbuf, Tsum, 1, 1);
    // v2 -> out, norms
    hipLaunchKernelGGL(k_v, dim3(L / 4, B), dim3(256), 0, stream,
                       spbuf, out, norms);
    hipLaunchKernelGGL(k_final, dim3(1), dim3(64), 0, stream, Tsum, norms, out);
}

// Round 9
// 259.381 us; speedup vs baseline: 1.8286x; 1.3774x over previous
//
#include <hip/hip_runtime.h>
#include <hip/hip_bf16.h>

#define B 16
#define L 64
#define P 1024
#define V 64
#define Q 16
#define LN64 4.158883083359672f

#define CHBC 16           // p per k_bc block
#define NCH_BC (P / CHBC) // 64

typedef unsigned short ushort8_t __attribute__((ext_vector_type(8)));

typedef const __attribute__((address_space(1))) void* gld_gptr_t;
typedef __attribute__((address_space(3))) void* gld_lptr_t;

static __device__ __forceinline__ float bf2f(ushort u) {
    return __uint_as_float(((unsigned int)u) << 16);
}
static __device__ __forceinline__ ushort f2bf(float f) {
    unsigned int x = __float_as_uint(f);
    unsigned int r = (x + 0x7fffu + ((x >> 16) & 1u)) >> 16;
    return (ushort)r;
}

static __device__ __forceinline__ float wsum64(float v) {
#pragma unroll
    for (int m = 32; m > 0; m >>= 1) v += __shfl_xor(v, m, 64);
    return v;
}
static __device__ __forceinline__ float wmax64(float v) {
#pragma unroll
    for (int m = 32; m > 0; m >>= 1) v = fmaxf(v, __shfl_xor(v, m, 64));
    return v;
}

// ---------------------------------------------------------------------------
// K_uhat v8: block = (p, l-half), 256 thr, 4 waves; wave w owns b [4w,4w+4),
// lane = v; x in f32 regs (as v2). W staged via global_load_lds into a
// WAVE-PRIVATE 3-deep LDS ring (no barriers in loop, no VGPR pipeline cost).
// Transpose-stage: instr k fetches lane*64 + k*16 -> LDS [slot][q4=k][lane],
// so ds_read_b128 per lane is 16B-stride within a 1KB row (bank-even).
// Counted s_waitcnt vmcnt(N), never 0 (queue: 2 stage-tiles + 2 store sets).
// uhat layout [b][l][p][v].
// ---------------------------------------------------------------------------
__global__ __launch_bounds__(256) void k_uhat(const float* __restrict__ Wt,
                                              const float* __restrict__ x,
                                              ushort* __restrict__ uhat) {
    const int t = threadIdx.x;
    const int w = t >> 6;          // b-group
    const int lane = t & 63;       // v
    const int p = blockIdx.x >> 1;
    const int l0 = (blockIdx.x & 1) * 32;

    __shared__ float xs[B * Q];                 // 1 KB
    __shared__ float4 wst[4][3][4][64];         // 48 KB: [wave][slot][q4][v]

    if (t < B * Q) {
        const int b = t >> 4, q = t & 15;
        xs[t] = x[((size_t)b * P + p) * Q + q];
    }
    __syncthreads();

    float xr[4][Q];                // wave's 4 b rows of x
#pragma unroll
    for (int i = 0; i < 4; ++i)
#pragma unroll
        for (int q = 0; q < Q; ++q) xr[i][q] = xs[(w * 4 + i) * Q + q];

    // per-lane global source base: W[l0][p][lane][0], advancing 4MB per l
    const char* gbase = (const char*)(Wt + ((size_t)l0 * P + p) * (V * Q)) + lane * 64;
    const size_t LSTRIDE = (size_t)P * V * Q * 4;   // 4 MB per l
    char* ldsb = (char*)&wst[w][0][0][0];

#define STAGE(li, slot)                                                       \
    {                                                                         \
        const char* g = gbase + (size_t)(li) * LSTRIDE;                       \
        char* lb = ldsb + (slot) * 4096;                                      \
        __builtin_amdgcn_global_load_lds((gld_gptr_t)(g + 0),  (gld_lptr_t)(lb + 0),    16, 0, 0); \
        __builtin_amdgcn_global_load_lds((gld_gptr_t)(g + 16), (gld_lptr_t)(lb + 1024), 16, 0, 0); \
        __builtin_amdgcn_global_load_lds((gld_gptr_t)(g + 32), (gld_lptr_t)(lb + 2048), 16, 0, 0); \
        __builtin_amdgcn_global_load_lds((gld_gptr_t)(g + 48), (gld_lptr_t)(lb + 3072), 16, 0, 0); \
    }

#define COMPUTE(li, slot)                                                     \
    {                                                                         \
        const float4* wr = (const float4*)(ldsb + (slot) * 4096);             \
        const float4 W0 = wr[0 * 64 + lane];                                  \
        const float4 W1 = wr[1 * 64 + lane];                                  \
        const float4 W2 = wr[2 * 64 + lane];                                  \
        const float4 W3 = wr[3 * 64 + lane];                                  \
        _Pragma("unroll")                                                     \
        for (int i = 0; i < 4; ++i) {                                         \
            float u = 0.f;                                                    \
            u = fmaf(W0.x, xr[i][0],  u); u = fmaf(W0.y, xr[i][1],  u);       \
            u = fmaf(W0.z, xr[i][2],  u); u = fmaf(W0.w, xr[i][3],  u);       \
            u = fmaf(W1.x, xr[i][4],  u); u = fmaf(W1.y, xr[i][5],  u);       \
            u = fmaf(W1.z, xr[i][6],  u); u = fmaf(W1.w, xr[i][7],  u);       \
            u = fmaf(W2.x, xr[i][8],  u); u = fmaf(W2.y, xr[i][9],  u);       \
            u = fmaf(W2.z, xr[i][10], u); u = fmaf(W2.w, xr[i][11], u);       \
            u = fmaf(W3.x, xr[i][12], u); u = fmaf(W3.y, xr[i][13], u);       \
            u = fmaf(W3.z, xr[i][14], u); u = fmaf(W3.w, xr[i][15], u);       \
            const int b = w * 4 + i;                                          \
            uhat[(((size_t)(b * L + (l0 + (li)))) * P + p) * V + lane] = f2bf(u); \
        }                                                                     \
    }

    STAGE(0, 0);
    STAGE(1, 1);

    // li = 0: queue {S0,S1}=8 -> wait(4) completes S0
    asm volatile("s_waitcnt vmcnt(4)" ::: "memory");
    __builtin_amdgcn_sched_barrier(0);
    STAGE(2, 2);
    COMPUTE(0, 0);

    // li = 1: queue {S1, st0, S2}=12 -> wait(8) completes S1
    asm volatile("s_waitcnt vmcnt(8)" ::: "memory");
    __builtin_amdgcn_sched_barrier(0);
    STAGE(3, 0);
    COMPUTE(1, 1);

    // steady state li = 2..30: queue {S(li), st(li-2), S(li+1), st(li-1)} = 16
#pragma unroll 3
    for (int li = 2; li <= 30; ++li) {
        asm volatile("s_waitcnt vmcnt(12)" ::: "memory");
        __builtin_amdgcn_sched_barrier(0);
        if (li <= 29) STAGE(li + 2, (li + 2) % 3);
        COMPUTE(li, li % 3);
    }

    // li = 31: queue {S31, st29, st30}=12 -> wait(8) completes S31
    asm volatile("s_waitcnt vmcnt(8)" ::: "memory");
    __builtin_amdgcn_sched_barrier(0);
    COMPUTE(31, 31 % 3);

#undef STAGE
#undef COMPUTE
}

// ---------------------------------------------------------------------------
// K_s: per (b,l) block, iter-0 only (uniform c). s[v] = (1/64) sum_p u[p,v],
// fused squash. Thread t owns (pl = t>>4, v0 = (t&15)*4); ushort4 loads.
// ---------------------------------------------------------------------------
__global__ __launch_bounds__(256) void k_s(const ushort* __restrict__ uhat,
                                           float* __restrict__ vout) {
    const int l = blockIdx.x, b = blockIdx.y;
    const int t = threadIdx.x;
    const int w = t >> 6, lane = t & 63;
    const int pl = t >> 4;      // 0..15
    const int vg = t & 15;      // v0 = vg*4

    __shared__ float4 sl[4][16];

    const ushort* up = uhat + ((size_t)(b * L + l)) * P * V + (size_t)pl * V + vg * 4;

    float4 acc = {0.f, 0.f, 0.f, 0.f};
#pragma unroll 8
    for (int i = 0; i < 64; ++i) {
        ushort4 u = *reinterpret_cast<const ushort4*>(up + (size_t)i * 16 * V);
        acc.x += bf2f(u.x); acc.y += bf2f(u.y);
        acc.z += bf2f(u.z); acc.w += bf2f(u.w);
    }
    acc.x *= (1.f / 64.f); acc.y *= (1.f / 64.f);
    acc.z *= (1.f / 64.f); acc.w *= (1.f / 64.f);
#pragma unroll
    for (int m = 16; m <= 32; m <<= 1) {
        acc.x += __shfl_xor(acc.x, m, 64);
        acc.y += __shfl_xor(acc.y, m, 64);
        acc.z += __shfl_xor(acc.z, m, 64);
        acc.w += __shfl_xor(acc.w, m, 64);
    }
    if (lane < 16) sl[w][vg] = acc;
    __syncthreads();
    if (w == 0 && lane < 16) {
        float4 s0 = sl[0][vg], s1 = sl[1][vg], s2 = sl[2][vg], s3 = sl[3][vg];
        float4 s;
        s.x = s0.x + s1.x + s2.x + s3.x;
        s.y = s0.y + s1.y + s2.y + s3.y;
        s.z = s0.z + s1.z + s2.z + s3.z;
        s.w = s0.w + s1.w + s2.w + s3.w;
        float sq = s.x * s.x + s.y * s.y + s.z * s.z + s.w * s.w;
        sq += __shfl_xor(sq, 1, 64);
        sq += __shfl_xor(sq, 2, 64);
        sq += __shfl_xor(sq, 4, 64);
        sq += __shfl_xor(sq, 8, 64);
        float f = sqrtf(sq) / (1.0f + sq);
        float4 o = {s.x * f, s.y * f, s.z * f, s.w * f};
        *reinterpret_cast<float4*>(vout + (size_t)(b * L + l) * V + vg * 4) = o;
    }
}

// ---------------------------------------------------------------------------
// K_bc v6: block = (ch of 16 p, b), 512 threads (8 waves). u tile kept in
// REGISTERS (ur[8][2] ushort8/thread); LDS only vsh+bl (20 KB) -> 2 blocks/CU.
// phase 1: all 16 coalesced 1KB u-loads issued early, dot with v -> bl[p][l].
// phase 2: softmax over l per p (each wave 2 p's); b-logit update; optional T.
// phase 3: s-partial from registers, butterfly over pl8 -> sp[b][ch][l][v].
// ---------------------------------------------------------------------------
__global__ __launch_bounds__(512, 4) void k_bc(const ushort* __restrict__ uhat,
                                               const float* __restrict__ vv,
                                               float* __restrict__ bbuf,
                                               float* __restrict__ sp,
                                               float* __restrict__ Tsum,
                                               int add_prev, int do_T) {
    const int ch = blockIdx.x, b = blockIdx.y;
    const int p0 = ch * CHBC;
    const int t = threadIdx.x;
    const int w = t >> 6, lane = t & 63;
    const int pl8 = lane >> 3;   // p-local
    const int vg8 = lane & 7;    // v-octet
    const int l0 = w * 8;

    __shared__ float vsh[L][V];         // 16 KB
    __shared__ float bl[CHBC][L + 1];   // logits, then c in place
    __shared__ float twv[8];

    {
        const float4* vvp = reinterpret_cast<const float4*>(vv + (size_t)b * L * V);
        float4* vshp = reinterpret_cast<float4*>(&vsh[0][0]);
#pragma unroll
        for (int i = 0; i < 2; ++i) vshp[t + i * 512] = vvp[t + i * 512];
    }

    ushort8_t ur[8][2];
    {
        const ushort* ubase = uhat + (((size_t)(b * L + l0)) * P + p0 + pl8) * V + vg8 * 8;
#pragma unroll
        for (int li = 0; li < 8; ++li) {
#pragma unroll
            for (int ph = 0; ph < 2; ++ph)
                ur[li][ph] = *reinterpret_cast<const ushort8_t*>(
                    ubase + ((size_t)li * P + ph * 8) * V);
        }
    }
    __syncthreads();

#pragma unroll
    for (int li = 0; li < 8; ++li) {
        const int l = l0 + li;
        const float4 va = *reinterpret_cast<const float4*>(&vsh[l][vg8 * 8]);
        const float4 vb = *reinterpret_cast<const float4*>(&vsh[l][vg8 * 8 + 4]);
#pragma unroll
        for (int ph = 0; ph < 2; ++ph) {
            float d;
            d = bf2f(ur[li][ph][0]) * va.x;
            d = fmaf(bf2f(ur[li][ph][1]), va.y, d);
            d = fmaf(bf2f(ur[li][ph][2]), va.z, d);
            d = fmaf(bf2f(ur[li][ph][3]), va.w, d);
            d = fmaf(bf2f(ur[li][ph][4]), vb.x, d);
            d = fmaf(bf2f(ur[li][ph][5]), vb.y, d);
            d = fmaf(bf2f(ur[li][ph][6]), vb.z, d);
            d = fmaf(bf2f(ur[li][ph][7]), vb.w, d);
            d += __shfl_xor(d, 1, 64);
            d += __shfl_xor(d, 2, 64);
            d += __shfl_xor(d, 4, 64);
            if (vg8 == 0) bl[ph * 8 + pl8][l] = d;
        }
    }
    __syncthreads();

    float tloc = 0.f;
#pragma unroll
    for (int pi = 0; pi < 2; ++pi) {
        const int pli = w * 2 + pi;
        const int p = p0 + pli;
        float bv = bl[pli][lane];
        float* bp = bbuf + ((size_t)b * P + p) * L;
        if (add_prev) bv += bp[lane];
        bp[lane] = bv;
        float m = wmax64(bv);
        float e = __expf(bv - m);
        float ssum = wsum64(e);
        float cc = e / ssum;
        bl[pli][lane] = cc;
        if (do_T) tloc += cc * __logf(64.0f * (cc + 1e-12f));
    }
    if (do_T) {
        float dsum = wsum64(tloc);
        if (lane == 0) twv[w] = dsum;
    }
    __syncthreads();
    if (do_T && t == 0) {
        float s8 = twv[0] + twv[1] + twv[2] + twv[3] +
                   twv[4] + twv[5] + twv[6] + twv[7];
        atomicAdd(Tsum, s8 * (1.0f / LN64));
    }

    float* spb = sp + (size_t)(b * NCH_BC + ch) * L * V;
#pragma unroll
    for (int li = 0; li < 8; ++li) {
        const int l = l0 + li;
        const float cA = bl[pl8][l];
        const float cB = bl[8 + pl8][l];
        float4 pa, pb;
        pa.x = cA * bf2f(ur[li][0][0]) + cB * bf2f(ur[li][1][0]);
        pa.y = cA * bf2f(ur[li][0][1]) + cB * bf2f(ur[li][1][1]);
        pa.z = cA * bf2f(ur[li][0][2]) + cB * bf2f(ur[li][1][2]);
        pa.w = cA * bf2f(ur[li][0][3]) + cB * bf2f(ur[li][1][3]);
        pb.x = cA * bf2f(ur[li][0][4]) + cB * bf2f(ur[li][1][4]);
        pb.y = cA * bf2f(ur[li][0][5]) + cB * bf2f(ur[li][1][5]);
        pb.z = cA * bf2f(ur[li][0][6]) + cB * bf2f(ur[li][1][6]);
        pb.w = cA * bf2f(ur[li][0][7]) + cB * bf2f(ur[li][1][7]);
#pragma unroll
        for (int m = 8; m <= 32; m <<= 1) {
            pa.x += __shfl_xor(pa.x, m, 64);
            pa.y += __shfl_xor(pa.y, m, 64);
            pa.z += __shfl_xor(pa.z, m, 64);
            pa.w += __shfl_xor(pa.w, m, 64);
            pb.x += __shfl_xor(pb.x, m, 64);
            pb.y += __shfl_xor(pb.y, m, 64);
            pb.z += __shfl_xor(pb.z, m, 64);
            pb.w += __shfl_xor(pb.w, m, 64);
        }
        if (pl8 == 0) {
            *reinterpret_cast<float4*>(spb + (size_t)l * V + vg8 * 8) = pa;
            *reinterpret_cast<float4*>(spb + (size_t)l * V + vg8 * 8 + 4) = pb;
        }
    }
}

// ---------------------------------------------------------------------------
// K_v: chunk-reduce + squash. sp[b][ch][l][v]. grid (L/4, B); wave w -> l.
// ---------------------------------------------------------------------------
__global__ __launch_bounds__(256) void k_v(const float* __restrict__ sp,
                                           float* __restrict__ vout,
                                           float* __restrict__ norms) {
    const int b = blockIdx.y;
    const int w = threadIdx.x >> 6, lane = threadIdx.x & 63;
    const int l = blockIdx.x * 4 + w;
    const float* p = sp + ((size_t)b * NCH_BC * L + l) * V + lane;
    float s = 0.f;
#pragma unroll 8
    for (int ch = 0; ch < NCH_BC; ++ch) s += p[(size_t)ch * L * V];
    float sq = wsum64(s * s);
    float f = sqrtf(sq) / (1.0f + sq);
    vout[((size_t)b * L + l) * V + lane] = s * f;
    if (norms && lane == 0) norms[b * L + l] = sq / (1.0f + sq);
}

// ---------------------------------------------------------------------------
// K_final: T and D. One block, 64 threads (lane = l).
// ---------------------------------------------------------------------------
__global__ void k_final(const float* __restrict__ Tsum,
                        const float* __restrict__ norms,
                        float* __restrict__ out) {
    const int lane = threadIdx.x & 63;
    float n[B];
    float sum = 0.f;
#pragma unroll
    for (int b = 0; b < B; ++b) { n[b] = norms[b * L + lane]; sum += n[b]; }
    const float mean = sum * (1.0f / B);
    float var = 0.f;
#pragma unroll
    for (int b = 0; b < B; ++b) { float d = n[b] - mean; var = fmaf(d, d, var); }
    var *= (1.0f / B);
    float sd = sqrtf(var);
    float D = wmax64(sd);
    if (lane == 0) {
        out[B * L * V] = Tsum[0] * (1.0f / (B * P));
        out[B * L * V + 1] = D;
    }
}

extern "C" void kernel_launch(void* const* d_in, const int* in_sizes, int n_in,
                              void* d_out, int out_size, void* d_ws, size_t ws_size,
                              hipStream_t stream) {
    const float* x = (const float*)d_in[0];   // (B,P,Q)
    const float* W = (const float*)d_in[1];   // (L,P,V,Q)
    float* out = (float*)d_out;               // v (B,L,V) then T, D

    char* ws = (char*)d_ws;
    ushort* uhat = (ushort*)ws;                        // [b][l][p][v] bf16 = 128 MB
    size_t off = (size_t)B * L * P * V * 2;
    float* spbuf = (float*)(ws + off); off += (size_t)B * NCH_BC * L * V * 4;  // 16 MB
    float* vbuf  = (float*)(ws + off); off += (size_t)B * L * V * 4;
    float* bbuf  = (float*)(ws + off); off += (size_t)B * P * L * 4;           // 4 MB [b][p][l]
    float* norms = (float*)(ws + off); off += (size_t)B * L * 4;
    float* Tsum  = (float*)(ws + off); off += 256;

    hipMemsetAsync(Tsum, 0, sizeof(float), stream);

    // u_hat (global_load_lds staged)
    hipLaunchKernelGGL(k_uhat, dim3(2048), dim3(256), 0, stream, W, x, uhat);
    // iter 0: uniform c -> v0
    hipLaunchKernelGGL(k_s, dim3(L, B), dim3(256), 0, stream, uhat, vbuf);
    // b1 = v0.u ; c1 ; partial s1 (fused, u in registers)
    hipLaunchKernelGGL(k_bc, dim3(NCH_BC, B), dim3(512), 0, stream,
                       uhat, vbuf, bbuf, spbuf, Tsum, 0, 0);
    // v1
    hipLaunchKernelGGL(k_v, dim3(L / 4, B), dim3(256), 0, stream,
                       spbuf, vbuf, (float*)nullptr);
    // b2 = b1 + v1.u ; c2 ; T partials ; partial s2
    hipLaunchKernelGGL(k_bc, dim3(NCH_BC, B), dim3(512), 0, stream,
                       uhat, vbuf, bbuf, spbuf, Tsum, 1, 1);
    // v2 -> out, norms
    hipLaunchKernelGGL(k_v, dim3(L / 4, B), dim3(256), 0, stream,
                       spbuf, out, norms);
    hipLaunchKernelGGL(k_final, dim3(1), dim3(64), 0, stream, Tsum, norms, out);
}

// Round 10
// 249.185 us; speedup vs baseline: 1.9034x; 1.0409x over previous
//
#include <hip/hip_runtime.h>
#include <hip/hip_bf16.h>

#define B 16
#define L 64
#define P 1024
#define V 64
#define Q 16
#define LN64 4.158883083359672f

#define CHBC 16           // p per k_bc block
#define NCH_BC (P / CHBC) // 64

typedef unsigned short ushort8_t __attribute__((ext_vector_type(8)));

static __device__ __forceinline__ float bf2f(ushort u) {
    return __uint_as_float(((unsigned int)u) << 16);
}
static __device__ __forceinline__ ushort f2bf(float f) {
    unsigned int x = __float_as_uint(f);
    unsigned int r = (x + 0x7fffu + ((x >> 16) & 1u)) >> 16;
    return (ushort)r;
}
// packed bf16-pair helpers: word = bf16(lo) | bf16(hi)<<16
static __device__ __forceinline__ float pklo(unsigned int w) {
    return __uint_as_float(w << 16);
}
static __device__ __forceinline__ float pkhi(unsigned int w) {
    return __uint_as_float(w & 0xffff0000u);
}

static __device__ __forceinline__ float wsum64(float v) {
#pragma unroll
    for (int m = 32; m > 0; m >>= 1) v += __shfl_xor(v, m, 64);
    return v;
}
static __device__ __forceinline__ float wmax64(float v) {
#pragma unroll
    for (int m = 32; m > 0; m >>= 1) v = fmaxf(v, __shfl_xor(v, m, 64));
    return v;
}

// ---------------------------------------------------------------------------
// K_uhat v9: block = (p, l-half), 256 thr, 4 waves; wave w owns b [4w,4w+4),
// lane = v. k_bc's proven load pattern applied to the producer:
//  - groups of 4 l; 16 float4 W loads per group held in REGISTERS (64 VGPR)
//  - per-group order: wait(16) -> compute -> issue NEXT 16 loads -> stores.
//    Loads for g+1 precede stores of g in the vmcnt queue, so vmcnt(16)
//    retires loads without waiting on store acks (single in-order vmcnt on
//    CDNA; interleaved stores were the v2/v4/v8 throttle).
//  - sched_barrier(0) pins each section (round-8 lesson: scheduler otherwise
//    collapses liveness to 48 VGPR and serializes loads).
// x packed as bf16 pairs (32 VGPR; accuracy validated round 8).
// uhat layout [b][l][p][v].
// ---------------------------------------------------------------------------
__global__ __launch_bounds__(256) void k_uhat(const float* __restrict__ Wt,
                                              const float* __restrict__ x,
                                              ushort* __restrict__ uhat) {
    const int t = threadIdx.x;
    const int w = t >> 6;          // b-group
    const int lane = t & 63;       // v
    const int p = blockIdx.x >> 1;
    const int l0 = (blockIdx.x & 1) * 32;

    __shared__ float xs[B * Q];    // 1 KB
    {
        const int b = t >> 4, q = t & 15;
        xs[t] = x[((size_t)b * P + p) * Q + q];
    }
    __syncthreads();

    // pack this wave's 4 b-rows of x as bf16 pairs
    unsigned int xp[4][8];
#pragma unroll
    for (int i = 0; i < 4; ++i) {
        const int b = w * 4 + i;
#pragma unroll
        for (int j = 0; j < 8; ++j) {
            unsigned int lo = f2bf(xs[b * Q + 2 * j]);
            unsigned int hi = f2bf(xs[b * Q + 2 * j + 1]);
            xp[i][j] = lo | (hi << 16);
        }
    }

    const float4* Wp0 = reinterpret_cast<const float4*>(Wt);

    float4 Wr[16];    // 4 l x 4 q4 (single-buffered)
    ushort uo[16];    // 4 l x 4 b outputs awaiting store

#define LOADG(g)                                                             \
    {                                                                        \
        _Pragma("unroll")                                                    \
        for (int jl = 0; jl < 4; ++jl) {                                     \
            const float4* wp = Wp0 +                                         \
                (((size_t)(l0 + (g) * 4 + jl) * P + p) * V + lane) * 4;      \
            Wr[jl * 4 + 0] = wp[0];                                          \
            Wr[jl * 4 + 1] = wp[1];                                          \
            Wr[jl * 4 + 2] = wp[2];                                          \
            Wr[jl * 4 + 3] = wp[3];                                          \
        }                                                                    \
    }

#define COMPUTEG()                                                           \
    {                                                                        \
        _Pragma("unroll")                                                    \
        for (int jl = 0; jl < 4; ++jl) {                                     \
            _Pragma("unroll")                                                \
            for (int i = 0; i < 4; ++i) {                                    \
                float u = 0.f;                                               \
                _Pragma("unroll")                                            \
                for (int j = 0; j < 8; ++j) {                                \
                    const float4 Wq = Wr[jl * 4 + (j >> 1)];                 \
                    const float wlo = (j & 1) ? Wq.z : Wq.x;                 \
                    const float whi = (j & 1) ? Wq.w : Wq.y;                 \
                    u = fmaf(wlo, pklo(xp[i][j]), u);                        \
                    u = fmaf(whi, pkhi(xp[i][j]), u);                        \
                }                                                            \
                uo[jl * 4 + i] = f2bf(u);                                    \
            }                                                                \
        }                                                                    \
    }

#define STOREG(g)                                                            \
    {                                                                        \
        _Pragma("unroll")                                                    \
        for (int jl = 0; jl < 4; ++jl) {                                     \
            _Pragma("unroll")                                                \
            for (int i = 0; i < 4; ++i) {                                    \
                const int b = w * 4 + i;                                     \
                const int l = l0 + (g) * 4 + jl;                             \
                uhat[(((size_t)(b * L + l)) * P + p) * V + lane] =           \
                    uo[jl * 4 + i];                                          \
            }                                                                \
        }                                                                    \
    }

    LOADG(0);
    asm volatile("s_waitcnt vmcnt(0)" ::: "memory");
    __builtin_amdgcn_sched_barrier(0);
    COMPUTEG();
    __builtin_amdgcn_sched_barrier(0);
    LOADG(1);
    __builtin_amdgcn_sched_barrier(0);
    STOREG(0);

#pragma unroll 1
    for (int g = 1; g < 7; ++g) {
        // queue: [S(g-2) drain, L(g) 16, S(g-1) 16] -> vmcnt(16) retires L(g)
        asm volatile("s_waitcnt vmcnt(16)" ::: "memory");
        __builtin_amdgcn_sched_barrier(0);
        COMPUTEG();
        __builtin_amdgcn_sched_barrier(0);
        LOADG(g + 1);
        __builtin_amdgcn_sched_barrier(0);
        STOREG(g);
    }

    asm volatile("s_waitcnt vmcnt(16)" ::: "memory");
    __builtin_amdgcn_sched_barrier(0);
    COMPUTEG();
    STOREG(7);
#undef LOADG
#undef COMPUTEG
#undef STOREG
}

// ---------------------------------------------------------------------------
// K_s: per (b,l) block, iter-0 only (uniform c). s[v] = (1/64) sum_p u[p,v],
// fused squash. Thread t owns (pl = t>>4, v0 = (t&15)*4); ushort4 loads.
// ---------------------------------------------------------------------------
__global__ __launch_bounds__(256) void k_s(const ushort* __restrict__ uhat,
                                           float* __restrict__ vout) {
    const int l = blockIdx.x, b = blockIdx.y;
    const int t = threadIdx.x;
    const int w = t >> 6, lane = t & 63;
    const int pl = t >> 4;      // 0..15
    const int vg = t & 15;      // v0 = vg*4

    __shared__ float4 sl[4][16];

    const ushort* up = uhat + ((size_t)(b * L + l)) * P * V + (size_t)pl * V + vg * 4;

    float4 acc = {0.f, 0.f, 0.f, 0.f};
#pragma unroll 8
    for (int i = 0; i < 64; ++i) {
        ushort4 u = *reinterpret_cast<const ushort4*>(up + (size_t)i * 16 * V);
        acc.x += bf2f(u.x); acc.y += bf2f(u.y);
        acc.z += bf2f(u.z); acc.w += bf2f(u.w);
    }
    acc.x *= (1.f / 64.f); acc.y *= (1.f / 64.f);
    acc.z *= (1.f / 64.f); acc.w *= (1.f / 64.f);
#pragma unroll
    for (int m = 16; m <= 32; m <<= 1) {
        acc.x += __shfl_xor(acc.x, m, 64);
        acc.y += __shfl_xor(acc.y, m, 64);
        acc.z += __shfl_xor(acc.z, m, 64);
        acc.w += __shfl_xor(acc.w, m, 64);
    }
    if (lane < 16) sl[w][vg] = acc;
    __syncthreads();
    if (w == 0 && lane < 16) {
        float4 s0 = sl[0][vg], s1 = sl[1][vg], s2 = sl[2][vg], s3 = sl[3][vg];
        float4 s;
        s.x = s0.x + s1.x + s2.x + s3.x;
        s.y = s0.y + s1.y + s2.y + s3.y;
        s.z = s0.z + s1.z + s2.z + s3.z;
        s.w = s0.w + s1.w + s2.w + s3.w;
        float sq = s.x * s.x + s.y * s.y + s.z * s.z + s.w * s.w;
        sq += __shfl_xor(sq, 1, 64);
        sq += __shfl_xor(sq, 2, 64);
        sq += __shfl_xor(sq, 4, 64);
        sq += __shfl_xor(sq, 8, 64);
        float f = sqrtf(sq) / (1.0f + sq);
        float4 o = {s.x * f, s.y * f, s.z * f, s.w * f};
        *reinterpret_cast<float4*>(vout + (size_t)(b * L + l) * V + vg * 4) = o;
    }
}

// ---------------------------------------------------------------------------
// K_bc v6: block = (ch of 16 p, b), 512 threads (8 waves). u tile kept in
// REGISTERS (ur[8][2] ushort8/thread); LDS only vsh+bl (20 KB) -> 2 blocks/CU.
// phase 1: all 16 coalesced 1KB u-loads issued early, dot with v -> bl[p][l].
// phase 2: softmax over l per p (each wave 2 p's); b-logit update; optional T.
// phase 3: s-partial from registers, butterfly over pl8 -> sp[b][ch][l][v].
// ---------------------------------------------------------------------------
__global__ __launch_bounds__(512, 4) void k_bc(const ushort* __restrict__ uhat,
                                               const float* __restrict__ vv,
                                               float* __restrict__ bbuf,
                                               float* __restrict__ sp,
                                               float* __restrict__ Tsum,
                                               int add_prev, int do_T) {
    const int ch = blockIdx.x, b = blockIdx.y;
    const int p0 = ch * CHBC;
    const int t = threadIdx.x;
    const int w = t >> 6, lane = t & 63;
    const int pl8 = lane >> 3;   // p-local
    const int vg8 = lane & 7;    // v-octet
    const int l0 = w * 8;

    __shared__ float vsh[L][V];         // 16 KB
    __shared__ float bl[CHBC][L + 1];   // logits, then c in place
    __shared__ float twv[8];

    {
        const float4* vvp = reinterpret_cast<const float4*>(vv + (size_t)b * L * V);
        float4* vshp = reinterpret_cast<float4*>(&vsh[0][0]);
#pragma unroll
        for (int i = 0; i < 2; ++i) vshp[t + i * 512] = vvp[t + i * 512];
    }

    ushort8_t ur[8][2];
    {
        const ushort* ubase = uhat + (((size_t)(b * L + l0)) * P + p0 + pl8) * V + vg8 * 8;
#pragma unroll
        for (int li = 0; li < 8; ++li) {
#pragma unroll
            for (int ph = 0; ph < 2; ++ph)
                ur[li][ph] = *reinterpret_cast<const ushort8_t*>(
                    ubase + ((size_t)li * P + ph * 8) * V);
        }
    }
    __syncthreads();

#pragma unroll
    for (int li = 0; li < 8; ++li) {
        const int l = l0 + li;
        const float4 va = *reinterpret_cast<const float4*>(&vsh[l][vg8 * 8]);
        const float4 vb = *reinterpret_cast<const float4*>(&vsh[l][vg8 * 8 + 4]);
#pragma unroll
        for (int ph = 0; ph < 2; ++ph) {
            float d;
            d = bf2f(ur[li][ph][0]) * va.x;
            d = fmaf(bf2f(ur[li][ph][1]), va.y, d);
            d = fmaf(bf2f(ur[li][ph][2]), va.z, d);
            d = fmaf(bf2f(ur[li][ph][3]), va.w, d);
            d = fmaf(bf2f(ur[li][ph][4]), vb.x, d);
            d = fmaf(bf2f(ur[li][ph][5]), vb.y, d);
            d = fmaf(bf2f(ur[li][ph][6]), vb.z, d);
            d = fmaf(bf2f(ur[li][ph][7]), vb.w, d);
            d += __shfl_xor(d, 1, 64);
            d += __shfl_xor(d, 2, 64);
            d += __shfl_xor(d, 4, 64);
            if (vg8 == 0) bl[ph * 8 + pl8][l] = d;
        }
    }
    __syncthreads();

    float tloc = 0.f;
#pragma unroll
    for (int pi = 0; pi < 2; ++pi) {
        const int pli = w * 2 + pi;
        const int p = p0 + pli;
        float bv = bl[pli][lane];
        float* bp = bbuf + ((size_t)b * P + p) * L;
        if (add_prev) bv += bp[lane];
        bp[lane] = bv;
        float m = wmax64(bv);
        float e = __expf(bv - m);
        float ssum = wsum64(e);
        float cc = e / ssum;
        bl[pli][lane] = cc;
        if (do_T) tloc += cc * __logf(64.0f * (cc + 1e-12f));
    }
    if (do_T) {
        float dsum = wsum64(tloc);
        if (lane == 0) twv[w] = dsum;
    }
    __syncthreads();
    if (do_T && t == 0) {
        float s8 = twv[0] + twv[1] + twv[2] + twv[3] +
                   twv[4] + twv[5] + twv[6] + twv[7];
        atomicAdd(Tsum, s8 * (1.0f / LN64));
    }

    float* spb = sp + (size_t)(b * NCH_BC + ch) * L * V;
#pragma unroll
    for (int li = 0; li < 8; ++li) {
        const int l = l0 + li;
        const float cA = bl[pl8][l];
        const float cB = bl[8 + pl8][l];
        float4 pa, pb;
        pa.x = cA * bf2f(ur[li][0][0]) + cB * bf2f(ur[li][1][0]);
        pa.y = cA * bf2f(ur[li][0][1]) + cB * bf2f(ur[li][1][1]);
        pa.z = cA * bf2f(ur[li][0][2]) + cB * bf2f(ur[li][1][2]);
        pa.w = cA * bf2f(ur[li][0][3]) + cB * bf2f(ur[li][1][3]);
        pb.x = cA * bf2f(ur[li][0][4]) + cB * bf2f(ur[li][1][4]);
        pb.y = cA * bf2f(ur[li][0][5]) + cB * bf2f(ur[li][1][5]);
        pb.z = cA * bf2f(ur[li][0][6]) + cB * bf2f(ur[li][1][6]);
        pb.w = cA * bf2f(ur[li][0][7]) + cB * bf2f(ur[li][1][7]);
#pragma unroll
        for (int m = 8; m <= 32; m <<= 1) {
            pa.x += __shfl_xor(pa.x, m, 64);
            pa.y += __shfl_xor(pa.y, m, 64);
            pa.z += __shfl_xor(pa.z, m, 64);
            pa.w += __shfl_xor(pa.w, m, 64);
            pb.x += __shfl_xor(pb.x, m, 64);
            pb.y += __shfl_xor(pb.y, m, 64);
            pb.z += __shfl_xor(pb.z, m, 64);
            pb.w += __shfl_xor(pb.w, m, 64);
        }
        if (pl8 == 0) {
            *reinterpret_cast<float4*>(spb + (size_t)l * V + vg8 * 8) = pa;
            *reinterpret_cast<float4*>(spb + (size_t)l * V + vg8 * 8 + 4) = pb;
        }
    }
}

// ---------------------------------------------------------------------------
// K_v: chunk-reduce + squash. sp[b][ch][l][v]. grid (L/4, B); wave w -> l.
// ---------------------------------------------------------------------------
__global__ __launch_bounds__(256) void k_v(const float* __restrict__ sp,
                                           float* __restrict__ vout,
                                           float* __restrict__ norms) {
    const int b = blockIdx.y;
    const int w = threadIdx.x >> 6, lane = threadIdx.x & 63;
    const int l = blockIdx.x * 4 + w;
    const float* p = sp + ((size_t)b * NCH_BC * L + l) * V + lane;
    float s = 0.f;
#pragma unroll 8
    for (int ch = 0; ch < NCH_BC; ++ch) s += p[(size_t)ch * L * V];
    float sq = wsum64(s * s);
    float f = sqrtf(sq) / (1.0f + sq);
    vout[((size_t)b * L + l) * V + lane] = s * f;
    if (norms && lane == 0) norms[b * L + l] = sq / (1.0f + sq);
}

// ---------------------------------------------------------------------------
// K_final: T and D. One block, 64 threads (lane = l).
// ---------------------------------------------------------------------------
__global__ void k_final(const float* __restrict__ Tsum,
                        const float* __restrict__ norms,
                        float* __restrict__ out) {
    const int lane = threadIdx.x & 63;
    float n[B];
    float sum = 0.f;
#pragma unroll
    for (int b = 0; b < B; ++b) { n[b] = norms[b * L + lane]; sum += n[b]; }
    const float mean = sum * (1.0f / B);
    float var = 0.f;
#pragma unroll
    for (int b = 0; b < B; ++b) { float d = n[b] - mean; var = fmaf(d, d, var); }
    var *= (1.0f / B);
    float sd = sqrtf(var);
    float D = wmax64(sd);
    if (lane == 0) {
        out[B * L * V] = Tsum[0] * (1.0f / (B * P));
        out[B * L * V + 1] = D;
    }
}

extern "C" void kernel_launch(void* const* d_in, const int* in_sizes, int n_in,
                              void* d_out, int out_size, void* d_ws, size_t ws_size,
                              hipStream_t stream) {
    const float* x = (const float*)d_in[0];   // (B,P,Q)
    const float* W = (const float*)d_in[1];   // (L,P,V,Q)
    float* out = (float*)d_out;               // v (B,L,V) then T, D

    char* ws = (char*)d_ws;
    ushort* uhat = (ushort*)ws;                        // [b][l][p][v] bf16 = 128 MB
    size_t off = (size_t)B * L * P * V * 2;
    float* spbuf = (float*)(ws + off); off += (size_t)B * NCH_BC * L * V * 4;  // 16 MB
    float* vbuf  = (float*)(ws + off); off += (size_t)B * L * V * 4;
    float* bbuf  = (float*)(ws + off); off += (size_t)B * P * L * 4;           // 4 MB [b][p][l]
    float* norms = (float*)(ws + off); off += (size_t)B * L * 4;
    float* Tsum  = (float*)(ws + off); off += 256;

    hipMemsetAsync(Tsum, 0, sizeof(float), stream);

    // u_hat (batched loads, stores decoupled from load waits)
    hipLaunchKernelGGL(k_uhat, dim3(2048), dim3(256), 0, stream, W, x, uhat);
    // iter 0: uniform c -> v0
    hipLaunchKernelGGL(k_s, dim3(L, B), dim3(256), 0, stream, uhat, vbuf);
    // b1 = v0.u ; c1 ; partial s1 (fused, u in registers)
    hipLaunchKernelGGL(k_bc, dim3(NCH_BC, B), dim3(512), 0, stream,
                       uhat, vbuf, bbuf, spbuf, Tsum, 0, 0);
    // v1
    hipLaunchKernelGGL(k_v, dim3(L / 4, B), dim3(256), 0, stream,
                       spbuf, vbuf, (float*)nullptr);
    // b2 = b1 + v1.u ; c2 ; T partials ; partial s2
    hipLaunchKernelGGL(k_bc, dim3(NCH_BC, B), dim3(512), 0, stream,
                       uhat, vbuf, bbuf, spbuf, Tsum, 1, 1);
    // v2 -> out, norms
    hipLaunchKernelGGL(k_v, dim3(L / 4, B), dim3(256), 0, stream,
                       spbuf, out, norms);
    hipLaunchKernelGGL(k_final, dim3(1), dim3(64), 0, stream, Tsum, norms, out);
}

// Round 11
// 228.536 us; speedup vs baseline: 2.0754x; 1.0904x over previous
//
#include <hip/hip_runtime.h>
#include <hip/hip_bf16.h>

#define B 16
#define L 64
#define P 1024
#define V 64
#define Q 16
#define LN64 4.158883083359672f

#define CHBC 16           // p per k_bc block
#define NCH_BC (P / CHBC) // 64

typedef unsigned short ushort8_t __attribute__((ext_vector_type(8)));

typedef const __attribute__((address_space(1))) void* gld_gptr_t;
typedef __attribute__((address_space(3))) void* gld_lptr_t;

static __device__ __forceinline__ float bf2f(ushort u) {
    return __uint_as_float(((unsigned int)u) << 16);
}
static __device__ __forceinline__ ushort f2bf(float f) {
    unsigned int x = __float_as_uint(f);
    unsigned int r = (x + 0x7fffu + ((x >> 16) & 1u)) >> 16;
    return (ushort)r;
}
// packed bf16-pair helpers: word = bf16(lo) | bf16(hi)<<16
static __device__ __forceinline__ float pklo(unsigned int w) {
    return __uint_as_float(w << 16);
}
static __device__ __forceinline__ float pkhi(unsigned int w) {
    return __uint_as_float(w & 0xffff0000u);
}

static __device__ __forceinline__ float wsum64(float v) {
#pragma unroll
    for (int m = 32; m > 0; m >>= 1) v += __shfl_xor(v, m, 64);
    return v;
}
static __device__ __forceinline__ float wmax64(float v) {
#pragma unroll
    for (int m = 32; m > 0; m >>= 1) v = fmaxf(v, __shfl_xor(v, m, 64));
    return v;
}

// ---------------------------------------------------------------------------
// K_uhat v10: block = (p, l-half), 256 thr, 4 waves; wave w owns b [4w,4w+4),
// lane = v. THE fix: fully-coalesced W reads.
//  - Stage W[l][p][*][*] (4 KB) via global_load_lds: wave w stages quarter w
//    with per-lane source src(i) = (i&~3)|((i&3)^((i>>3)&3)) chunks of 16 B
//    -> each instruction reads a CONTIGUOUS 1 KB (prior rounds: stride-64
//    gather = 4x sector waste, the persistent 1.6-2.6 TB/s limiter).
//  - LDS dest linear (HW requirement); read side applies the matching XOR:
//    lane v reads q4 at byte v*64 + (q4^((v>>1)&3))*16 -> 8 lanes per
//    bank-group = conflict-free (un-swizzled would be 32-way).
//  - 4-slot ring, 2-l prefetch, raw s_barrier + counted vmcnt (never 0 in
//    steady state; stores drain behind the stage in the in-order queue).
// uhat layout [b][l][p][v]. x packed bf16 pairs (validated rounds 8-10).
// ---------------------------------------------------------------------------
__global__ __launch_bounds__(256) void k_uhat(const float* __restrict__ Wt,
                                              const float* __restrict__ x,
                                              ushort* __restrict__ uhat) {
    const int t = threadIdx.x;
    const int w = t >> 6;          // b-group / stage-quarter
    const int lane = t & 63;       // v
    const int p = blockIdx.x >> 1;
    const int l0 = (blockIdx.x & 1) * 32;

    __shared__ float xs[B * Q];        // 1 KB
    __shared__ float wls[4][1024];     // 16 KB: 4 slots x 4 KB

    {
        const int b = t >> 4, q = t & 15;
        xs[t] = x[((size_t)b * P + p) * Q + q];
    }
    __syncthreads();

    // pack this wave's 4 b-rows of x as bf16 pairs (32 VGPR)
    unsigned int xp[4][8];
#pragma unroll
    for (int i = 0; i < 4; ++i) {
        const int b = w * 4 + i;
#pragma unroll
        for (int j = 0; j < 8; ++j) {
            unsigned int lo = f2bf(xs[b * Q + 2 * j]);
            unsigned int hi = f2bf(xs[b * Q + 2 * j + 1]);
            xp[i][j] = lo | (hi << 16);
        }
    }

    // inverse-swizzled per-lane global source (16B chunk index i = w*64+lane)
    const int i_idx = w * 64 + lane;
    const int src_chunk = (i_idx & ~3) | ((i_idx & 3) ^ ((i_idx >> 3) & 3));
    const char* gW = (const char*)Wt + ((size_t)l0 * P + p) * (V * Q * 4)
                     + (size_t)src_chunk * 16;
    const size_t LSTRIDE = (size_t)P * V * Q * 4;   // 4 MB per l
    const int xsw = (lane >> 1) & 3;                // read-side XOR

#define STAGE(li)                                                             \
    __builtin_amdgcn_global_load_lds(                                         \
        (gld_gptr_t)(gW + (size_t)(li) * LSTRIDE),                            \
        (gld_lptr_t)&wls[(li) & 3][w * 256], 16, 0, 0);

#define COMPUTE(li)                                                           \
    {                                                                         \
        const char* sb = (const char*)&wls[(li) & 3][0] + lane * 64;          \
        float4 Wr[4];                                                         \
        Wr[0] = *(const float4*)(sb + ((0 ^ xsw) << 4));                      \
        Wr[1] = *(const float4*)(sb + ((1 ^ xsw) << 4));                      \
        Wr[2] = *(const float4*)(sb + ((2 ^ xsw) << 4));                      \
        Wr[3] = *(const float4*)(sb + ((3 ^ xsw) << 4));                      \
        _Pragma("unroll")                                                     \
        for (int i = 0; i < 4; ++i) {                                         \
            float u = 0.f;                                                    \
            _Pragma("unroll")                                                 \
            for (int j = 0; j < 8; ++j) {                                     \
                const float4 Wq = Wr[j >> 1];                                 \
                const float wlo = (j & 1) ? Wq.z : Wq.x;                      \
                const float whi = (j & 1) ? Wq.w : Wq.y;                      \
                u = fmaf(wlo, pklo(xp[i][j]), u);                             \
                u = fmaf(whi, pkhi(xp[i][j]), u);                             \
            }                                                                 \
            uhat[(((size_t)((w * 4 + i) * L + l0 + (li))) * P + p) * V + lane] \
                = f2bf(u);                                                    \
        }                                                                     \
    }

#define SYNC(N)                                                               \
    asm volatile("s_waitcnt vmcnt(" #N ")" ::: "memory");                     \
    __builtin_amdgcn_sched_barrier(0);                                        \
    __builtin_amdgcn_s_barrier();                                             \
    __builtin_amdgcn_sched_barrier(0);

    STAGE(0);
    STAGE(1);

    // l=0: queue [S0,S1] -> wait(1) retires S0
    SYNC(1);
    STAGE(2);
    COMPUTE(0);
    // l=1: queue [S1, st0 x4, S2] = 6 -> wait(5) retires S1
    SYNC(5);
    STAGE(3);
    COMPUTE(1);

    // steady l=2..29: queue [S(l), st(l-2) x4, S(l+1), st(l-1) x4] = 10
#pragma unroll 1
    for (int li = 2; li <= 29; ++li) {
        SYNC(9);
        STAGE(li + 2);
        COMPUTE(li);
    }

    // l=30: queue [S30, st28 x4, S31, st29 x4] = 10 -> wait(9) retires S30
    SYNC(9);
    COMPUTE(30);
    // l=31: queue [S31, st29 x4, st30 x4] = 9 -> wait(8) retires S31
    SYNC(8);
    COMPUTE(31);

#undef STAGE
#undef COMPUTE
#undef SYNC
}

// ---------------------------------------------------------------------------
// K_s: per (b,l) block, iter-0 only (uniform c). s[v] = (1/64) sum_p u[p,v],
// fused squash. Thread t owns (pl = t>>4, v0 = (t&15)*4); ushort4 loads.
// ---------------------------------------------------------------------------
__global__ __launch_bounds__(256) void k_s(const ushort* __restrict__ uhat,
                                           float* __restrict__ vout) {
    const int l = blockIdx.x, b = blockIdx.y;
    const int t = threadIdx.x;
    const int w = t >> 6, lane = t & 63;
    const int pl = t >> 4;      // 0..15
    const int vg = t & 15;      // v0 = vg*4

    __shared__ float4 sl[4][16];

    const ushort* up = uhat + ((size_t)(b * L + l)) * P * V + (size_t)pl * V + vg * 4;

    float4 acc = {0.f, 0.f, 0.f, 0.f};
#pragma unroll 8
    for (int i = 0; i < 64; ++i) {
        ushort4 u = *reinterpret_cast<const ushort4*>(up + (size_t)i * 16 * V);
        acc.x += bf2f(u.x); acc.y += bf2f(u.y);
        acc.z += bf2f(u.z); acc.w += bf2f(u.w);
    }
    acc.x *= (1.f / 64.f); acc.y *= (1.f / 64.f);
    acc.z *= (1.f / 64.f); acc.w *= (1.f / 64.f);
#pragma unroll
    for (int m = 16; m <= 32; m <<= 1) {
        acc.x += __shfl_xor(acc.x, m, 64);
        acc.y += __shfl_xor(acc.y, m, 64);
        acc.z += __shfl_xor(acc.z, m, 64);
        acc.w += __shfl_xor(acc.w, m, 64);
    }
    if (lane < 16) sl[w][vg] = acc;
    __syncthreads();
    if (w == 0 && lane < 16) {
        float4 s0 = sl[0][vg], s1 = sl[1][vg], s2 = sl[2][vg], s3 = sl[3][vg];
        float4 s;
        s.x = s0.x + s1.x + s2.x + s3.x;
        s.y = s0.y + s1.y + s2.y + s3.y;
        s.z = s0.z + s1.z + s2.z + s3.z;
        s.w = s0.w + s1.w + s2.w + s3.w;
        float sq = s.x * s.x + s.y * s.y + s.z * s.z + s.w * s.w;
        sq += __shfl_xor(sq, 1, 64);
        sq += __shfl_xor(sq, 2, 64);
        sq += __shfl_xor(sq, 4, 64);
        sq += __shfl_xor(sq, 8, 64);
        float f = sqrtf(sq) / (1.0f + sq);
        float4 o = {s.x * f, s.y * f, s.z * f, s.w * f};
        *reinterpret_cast<float4*>(vout + (size_t)(b * L + l) * V + vg * 4) = o;
    }
}

// ---------------------------------------------------------------------------
// K_bc v6: block = (ch of 16 p, b), 512 threads (8 waves). u tile kept in
// REGISTERS (ur[8][2] ushort8/thread); LDS only vsh+bl (20 KB) -> 2 blocks/CU.
// phase 1: all 16 coalesced 1KB u-loads issued early, dot with v -> bl[p][l].
// phase 2: softmax over l per p (each wave 2 p's); b-logit update; optional T.
// phase 3: s-partial from registers, butterfly over pl8 -> sp[b][ch][l][v].
// ---------------------------------------------------------------------------
__global__ __launch_bounds__(512, 4) void k_bc(const ushort* __restrict__ uhat,
                                               const float* __restrict__ vv,
                                               float* __restrict__ bbuf,
                                               float* __restrict__ sp,
                                               float* __restrict__ Tsum,
                                               int add_prev, int do_T) {
    const int ch = blockIdx.x, b = blockIdx.y;
    const int p0 = ch * CHBC;
    const int t = threadIdx.x;
    const int w = t >> 6, lane = t & 63;
    const int pl8 = lane >> 3;   // p-local
    const int vg8 = lane & 7;    // v-octet
    const int l0 = w * 8;

    __shared__ float vsh[L][V];         // 16 KB
    __shared__ float bl[CHBC][L + 1];   // logits, then c in place
    __shared__ float twv[8];

    {
        const float4* vvp = reinterpret_cast<const float4*>(vv + (size_t)b * L * V);
        float4* vshp = reinterpret_cast<float4*>(&vsh[0][0]);
#pragma unroll
        for (int i = 0; i < 2; ++i) vshp[t + i * 512] = vvp[t + i * 512];
    }

    ushort8_t ur[8][2];
    {
        const ushort* ubase = uhat + (((size_t)(b * L + l0)) * P + p0 + pl8) * V + vg8 * 8;
#pragma unroll
        for (int li = 0; li < 8; ++li) {
#pragma unroll
            for (int ph = 0; ph < 2; ++ph)
                ur[li][ph] = *reinterpret_cast<const ushort8_t*>(
                    ubase + ((size_t)li * P + ph * 8) * V);
        }
    }
    __syncthreads();

#pragma unroll
    for (int li = 0; li < 8; ++li) {
        const int l = l0 + li;
        const float4 va = *reinterpret_cast<const float4*>(&vsh[l][vg8 * 8]);
        const float4 vb = *reinterpret_cast<const float4*>(&vsh[l][vg8 * 8 + 4]);
#pragma unroll
        for (int ph = 0; ph < 2; ++ph) {
            float d;
            d = bf2f(ur[li][ph][0]) * va.x;
            d = fmaf(bf2f(ur[li][ph][1]), va.y, d);
            d = fmaf(bf2f(ur[li][ph][2]), va.z, d);
            d = fmaf(bf2f(ur[li][ph][3]), va.w, d);
            d = fmaf(bf2f(ur[li][ph][4]), vb.x, d);
            d = fmaf(bf2f(ur[li][ph][5]), vb.y, d);
            d = fmaf(bf2f(ur[li][ph][6]), vb.z, d);
            d = fmaf(bf2f(ur[li][ph][7]), vb.w, d);
            d += __shfl_xor(d, 1, 64);
            d += __shfl_xor(d, 2, 64);
            d += __shfl_xor(d, 4, 64);
            if (vg8 == 0) bl[ph * 8 + pl8][l] = d;
        }
    }
    __syncthreads();

    float tloc = 0.f;
#pragma unroll
    for (int pi = 0; pi < 2; ++pi) {
        const int pli = w * 2 + pi;
        const int p = p0 + pli;
        float bv = bl[pli][lane];
        float* bp = bbuf + ((size_t)b * P + p) * L;
        if (add_prev) bv += bp[lane];
        bp[lane] = bv;
        float m = wmax64(bv);
        float e = __expf(bv - m);
        float ssum = wsum64(e);
        float cc = e / ssum;
        bl[pli][lane] = cc;
        if (do_T) tloc += cc * __logf(64.0f * (cc + 1e-12f));
    }
    if (do_T) {
        float dsum = wsum64(tloc);
        if (lane == 0) twv[w] = dsum;
    }
    __syncthreads();
    if (do_T && t == 0) {
        float s8 = twv[0] + twv[1] + twv[2] + twv[3] +
                   twv[4] + twv[5] + twv[6] + twv[7];
        atomicAdd(Tsum, s8 * (1.0f / LN64));
    }

    float* spb = sp + (size_t)(b * NCH_BC + ch) * L * V;
#pragma unroll
    for (int li = 0; li < 8; ++li) {
        const int l = l0 + li;
        const float cA = bl[pl8][l];
        const float cB = bl[8 + pl8][l];
        float4 pa, pb;
        pa.x = cA * bf2f(ur[li][0][0]) + cB * bf2f(ur[li][1][0]);
        pa.y = cA * bf2f(ur[li][0][1]) + cB * bf2f(ur[li][1][1]);
        pa.z = cA * bf2f(ur[li][0][2]) + cB * bf2f(ur[li][1][2]);
        pa.w = cA * bf2f(ur[li][0][3]) + cB * bf2f(ur[li][1][3]);
        pb.x = cA * bf2f(ur[li][0][4]) + cB * bf2f(ur[li][1][4]);
        pb.y = cA * bf2f(ur[li][0][5]) + cB * bf2f(ur[li][1][5]);
        pb.z = cA * bf2f(ur[li][0][6]) + cB * bf2f(ur[li][1][6]);
        pb.w = cA * bf2f(ur[li][0][7]) + cB * bf2f(ur[li][1][7]);
#pragma unroll
        for (int m = 8; m <= 32; m <<= 1) {
            pa.x += __shfl_xor(pa.x, m, 64);
            pa.y += __shfl_xor(pa.y, m, 64);
            pa.z += __shfl_xor(pa.z, m, 64);
            pa.w += __shfl_xor(pa.w, m, 64);
            pb.x += __shfl_xor(pb.x, m, 64);
            pb.y += __shfl_xor(pb.y, m, 64);
            pb.z += __shfl_xor(pb.z, m, 64);
            pb.w += __shfl_xor(pb.w, m, 64);
        }
        if (pl8 == 0) {
            *reinterpret_cast<float4*>(spb + (size_t)l * V + vg8 * 8) = pa;
            *reinterpret_cast<float4*>(spb + (size_t)l * V + vg8 * 8 + 4) = pb;
        }
    }
}

// ---------------------------------------------------------------------------
// K_v: chunk-reduce + squash. sp[b][ch][l][v]. grid (L/4, B); wave w -> l.
// ---------------------------------------------------------------------------
__global__ __launch_bounds__(256) void k_v(const float* __restrict__ sp,
                                           float* __restrict__ vout,
                                           float* __restrict__ norms) {
    const int b = blockIdx.y;
    const int w = threadIdx.x >> 6, lane = threadIdx.x & 63;
    const int l = blockIdx.x * 4 + w;
    const float* p = sp + ((size_t)b * NCH_BC * L + l) * V + lane;
    float s = 0.f;
#pragma unroll 8
    for (int ch = 0; ch < NCH_BC; ++ch) s += p[(size_t)ch * L * V];
    float sq = wsum64(s * s);
    float f = sqrtf(sq) / (1.0f + sq);
    vout[((size_t)b * L + l) * V + lane] = s * f;
    if (norms && lane == 0) norms[b * L + l] = sq / (1.0f + sq);
}

// ---------------------------------------------------------------------------
// K_final: T and D. One block, 64 threads (lane = l).
// ---------------------------------------------------------------------------
__global__ void k_final(const float* __restrict__ Tsum,
                        const float* __restrict__ norms,
                        float* __restrict__ out) {
    const int lane = threadIdx.x & 63;
    float n[B];
    float sum = 0.f;
#pragma unroll
    for (int b = 0; b < B; ++b) { n[b] = norms[b * L + lane]; sum += n[b]; }
    const float mean = sum * (1.0f / B);
    float var = 0.f;
#pragma unroll
    for (int b = 0; b < B; ++b) { float d = n[b] - mean; var = fmaf(d, d, var); }
    var *= (1.0f / B);
    float sd = sqrtf(var);
    float D = wmax64(sd);
    if (lane == 0) {
        out[B * L * V] = Tsum[0] * (1.0f / (B * P));
        out[B * L * V + 1] = D;
    }
}

extern "C" void kernel_launch(void* const* d_in, const int* in_sizes, int n_in,
                              void* d_out, int out_size, void* d_ws, size_t ws_size,
                              hipStream_t stream) {
    const float* x = (const float*)d_in[0];   // (B,P,Q)
    const float* W = (const float*)d_in[1];   // (L,P,V,Q)
    float* out = (float*)d_out;               // v (B,L,V) then T, D

    char* ws = (char*)d_ws;
    ushort* uhat = (ushort*)ws;                        // [b][l][p][v] bf16 = 128 MB
    size_t off = (size_t)B * L * P * V * 2;
    float* spbuf = (float*)(ws + off); off += (size_t)B * NCH_BC * L * V * 4;  // 16 MB
    float* vbuf  = (float*)(ws + off); off += (size_t)B * L * V * 4;
    float* bbuf  = (float*)(ws + off); off += (size_t)B * P * L * 4;           // 4 MB [b][p][l]
    float* norms = (float*)(ws + off); off += (size_t)B * L * 4;
    float* Tsum  = (float*)(ws + off); off += 256;

    hipMemsetAsync(Tsum, 0, sizeof(float), stream);

    // u_hat (coalesced staged W reads)
    hipLaunchKernelGGL(k_uhat, dim3(2048), dim3(256), 0, stream, W, x, uhat);
    // iter 0: uniform c -> v0
    hipLaunchKernelGGL(k_s, dim3(L, B), dim3(256), 0, stream, uhat, vbuf);
    // b1 = v0.u ; c1 ; partial s1 (fused, u in registers)
    hipLaunchKernelGGL(k_bc, dim3(NCH_BC, B), dim3(512), 0, stream,
                       uhat, vbuf, bbuf, spbuf, Tsum, 0, 0);
    // v1
    hipLaunchKernelGGL(k_v, dim3(L / 4, B), dim3(256), 0, stream,
                       spbuf, vbuf, (float*)nullptr);
    // b2 = b1 + v1.u ; c2 ; T partials ; partial s2
    hipLaunchKernelGGL(k_bc, dim3(NCH_BC, B), dim3(512), 0, stream,
                       uhat, vbuf, bbuf, spbuf, Tsum, 1, 1);
    // v2 -> out, norms
    hipLaunchKernelGGL(k_v, dim3(L / 4, B), dim3(256), 0, stream,
                       spbuf, out, norms);
    hipLaunchKernelGGL(k_final, dim3(1), dim3(64), 0, stream, Tsum, norms, out);
}

// Round 12
// 228.348 us; speedup vs baseline: 2.0771x; 1.0008x over previous
//
#include <hip/hip_runtime.h>
#include <hip/hip_bf16.h>

#define B 16
#define L 64
#define P 1024
#define V 64
#define Q 16
#define LN64 4.158883083359672f

#define CHBC 16           // p per k_bc block
#define NCH_BC (P / CHBC) // 64

typedef unsigned short ushort8_t __attribute__((ext_vector_type(8)));

typedef const __attribute__((address_space(1))) void* gld_gptr_t;
typedef __attribute__((address_space(3))) void* gld_lptr_t;

static __device__ __forceinline__ float bf2f(ushort u) {
    return __uint_as_float(((unsigned int)u) << 16);
}
static __device__ __forceinline__ ushort f2bf(float f) {
    unsigned int x = __float_as_uint(f);
    unsigned int r = (x + 0x7fffu + ((x >> 16) & 1u)) >> 16;
    return (ushort)r;
}
// packed bf16-pair helpers: word = bf16(lo) | bf16(hi)<<16
static __device__ __forceinline__ float pklo(unsigned int w) {
    return __uint_as_float(w << 16);
}
static __device__ __forceinline__ float pkhi(unsigned int w) {
    return __uint_as_float(w & 0xffff0000u);
}

static __device__ __forceinline__ float wsum64(float v) {
#pragma unroll
    for (int m = 32; m > 0; m >>= 1) v += __shfl_xor(v, m, 64);
    return v;
}
static __device__ __forceinline__ float wmax64(float v) {
#pragma unroll
    for (int m = 32; m > 0; m >>= 1) v = fmaxf(v, __shfl_xor(v, m, 64));
    return v;
}

// ---------------------------------------------------------------------------
// K_uhat v11: v10 (coalesced global_load_lds staging, swizzled LDS read) with
// the vmcnt queue FIXED. v10's steady vmcnt(9) forced each iteration to
// retire ~2-iteration-old STORE ACKS (in-order queue: ..st(l-4),S(l),
// st(l-3),S(l+1)..) -- an HBM write-ack latency stall every l. v11 uses
// prefetch depth 3 (same 4-slot ring): queue oscillates 14->19 and the
// steady vmcnt(14) retires st(li-4)x4 + S(li); those stores are 4 iters
// (~1400 cyc) old = already ack'd -> no store stall on the critical path.
// Waits (exact queue replay): prologue 2,6,10; steady 14; tail 14,13,12.
// ---------------------------------------------------------------------------
__global__ __launch_bounds__(256) void k_uhat(const float* __restrict__ Wt,
                                              const float* __restrict__ x,
                                              ushort* __restrict__ uhat) {
    const int t = threadIdx.x;
    const int w = t >> 6;          // b-group / stage-quarter
    const int lane = t & 63;       // v
    const int p = blockIdx.x >> 1;
    const int l0 = (blockIdx.x & 1) * 32;

    __shared__ float xs[B * Q];        // 1 KB
    __shared__ float wls[4][1024];     // 16 KB: 4 slots x 4 KB

    {
        const int b = t >> 4, q = t & 15;
        xs[t] = x[((size_t)b * P + p) * Q + q];
    }
    __syncthreads();

    // pack this wave's 4 b-rows of x as bf16 pairs (32 VGPR)
    unsigned int xp[4][8];
#pragma unroll
    for (int i = 0; i < 4; ++i) {
        const int b = w * 4 + i;
#pragma unroll
        for (int j = 0; j < 8; ++j) {
            unsigned int lo = f2bf(xs[b * Q + 2 * j]);
            unsigned int hi = f2bf(xs[b * Q + 2 * j + 1]);
            xp[i][j] = lo | (hi << 16);
        }
    }

    // inverse-swizzled per-lane global source (16B chunk index i = w*64+lane)
    const int i_idx = w * 64 + lane;
    const int src_chunk = (i_idx & ~3) | ((i_idx & 3) ^ ((i_idx >> 3) & 3));
    const char* gW = (const char*)Wt + ((size_t)l0 * P + p) * (V * Q * 4)
                     + (size_t)src_chunk * 16;
    const size_t LSTRIDE = (size_t)P * V * Q * 4;   // 4 MB per l
    const int xsw = (lane >> 1) & 3;                // read-side XOR

#define STAGE(li)                                                             \
    __builtin_amdgcn_global_load_lds(                                         \
        (gld_gptr_t)(gW + (size_t)(li) * LSTRIDE),                            \
        (gld_lptr_t)&wls[(li) & 3][w * 256], 16, 0, 0);

#define COMPUTE(li)                                                           \
    {                                                                         \
        const char* sb = (const char*)&wls[(li) & 3][0] + lane * 64;          \
        float4 Wr[4];                                                         \
        Wr[0] = *(const float4*)(sb + ((0 ^ xsw) << 4));                      \
        Wr[1] = *(const float4*)(sb + ((1 ^ xsw) << 4));                      \
        Wr[2] = *(const float4*)(sb + ((2 ^ xsw) << 4));                      \
        Wr[3] = *(const float4*)(sb + ((3 ^ xsw) << 4));                      \
        _Pragma("unroll")                                                     \
        for (int i = 0; i < 4; ++i) {                                         \
            float u = 0.f;                                                    \
            _Pragma("unroll")                                                 \
            for (int j = 0; j < 8; ++j) {                                     \
                const float4 Wq = Wr[j >> 1];                                 \
                const float wlo = (j & 1) ? Wq.z : Wq.x;                      \
                const float whi = (j & 1) ? Wq.w : Wq.y;                      \
                u = fmaf(wlo, pklo(xp[i][j]), u);                             \
                u = fmaf(whi, pkhi(xp[i][j]), u);                             \
            }                                                                 \
            uhat[(((size_t)((w * 4 + i) * L + l0 + (li))) * P + p) * V + lane] \
                = f2bf(u);                                                    \
        }                                                                     \
    }

#define SYNC(N)                                                               \
    asm volatile("s_waitcnt vmcnt(" #N ")" ::: "memory");                     \
    __builtin_amdgcn_sched_barrier(0);                                        \
    __builtin_amdgcn_s_barrier();                                             \
    __builtin_amdgcn_sched_barrier(0);

    STAGE(0);
    STAGE(1);
    STAGE(2);

    // it0: Q=[S0,S1,S2] -> wait(2) retires S0
    SYNC(2);
    STAGE(3);
    COMPUTE(0);
    // it1: Q=[S1,S2,S3,st0x4]=7 -> wait(6) retires S1
    SYNC(6);
    STAGE(4);
    COMPUTE(1);
    // it2: Q=[S2,S3,st0x4,S4,st1x4]=11 -> wait(10) retires S2
    SYNC(10);
    STAGE(5);
    COMPUTE(2);

    // steady it3..28: Q entry=19=[st(l-4)x4,S(l),st(l-3)x4,S(l+1),st(l-2)x4,
    // S(l+2),st(l-1)x4] -> wait(14) retires st(l-4)x4 (ack'd, 4 iters old)
    // + S(l). Stage S(l+3).
#pragma unroll 1
    for (int li = 3; li <= 28; ++li) {
        SYNC(14);
        STAGE(li + 3);
        COMPUTE(li);
    }

    // it29: Q entry 19 -> wait(14) retires st25x4+S29 (no stage left)
    SYNC(14);
    COMPUTE(29);
    // it30: Q=[st26x4,S30,st27x4,S31,st28x4,st29x4]=18 -> wait(13)
    SYNC(13);
    COMPUTE(30);
    // it31: Q=[st27x4,S31,st28x4,st29x4,st30x4]=17 -> wait(12)
    SYNC(12);
    COMPUTE(31);

#undef STAGE
#undef COMPUTE
#undef SYNC
}

// ---------------------------------------------------------------------------
// K_s: per (b,l) block, iter-0 only (uniform c). s[v] = (1/64) sum_p u[p,v],
// fused squash. Thread t owns (pl = t>>4, v0 = (t&15)*4); ushort4 loads.
// ---------------------------------------------------------------------------
__global__ __launch_bounds__(256) void k_s(const ushort* __restrict__ uhat,
                                           float* __restrict__ vout) {
    const int l = blockIdx.x, b = blockIdx.y;
    const int t = threadIdx.x;
    const int w = t >> 6, lane = t & 63;
    const int pl = t >> 4;      // 0..15
    const int vg = t & 15;      // v0 = vg*4

    __shared__ float4 sl[4][16];

    const ushort* up = uhat + ((size_t)(b * L + l)) * P * V + (size_t)pl * V + vg * 4;

    float4 acc = {0.f, 0.f, 0.f, 0.f};
#pragma unroll 8
    for (int i = 0; i < 64; ++i) {
        ushort4 u = *reinterpret_cast<const ushort4*>(up + (size_t)i * 16 * V);
        acc.x += bf2f(u.x); acc.y += bf2f(u.y);
        acc.z += bf2f(u.z); acc.w += bf2f(u.w);
    }
    acc.x *= (1.f / 64.f); acc.y *= (1.f / 64.f);
    acc.z *= (1.f / 64.f); acc.w *= (1.f / 64.f);
#pragma unroll
    for (int m = 16; m <= 32; m <<= 1) {
        acc.x += __shfl_xor(acc.x, m, 64);
        acc.y += __shfl_xor(acc.y, m, 64);
        acc.z += __shfl_xor(acc.z, m, 64);
        acc.w += __shfl_xor(acc.w, m, 64);
    }
    if (lane < 16) sl[w][vg] = acc;
    __syncthreads();
    if (w == 0 && lane < 16) {
        float4 s0 = sl[0][vg], s1 = sl[1][vg], s2 = sl[2][vg], s3 = sl[3][vg];
        float4 s;
        s.x = s0.x + s1.x + s2.x + s3.x;
        s.y = s0.y + s1.y + s2.y + s3.y;
        s.z = s0.z + s1.z + s2.z + s3.z;
        s.w = s0.w + s1.w + s2.w + s3.w;
        float sq = s.x * s.x + s.y * s.y + s.z * s.z + s.w * s.w;
        sq += __shfl_xor(sq, 1, 64);
        sq += __shfl_xor(sq, 2, 64);
        sq += __shfl_xor(sq, 4, 64);
        sq += __shfl_xor(sq, 8, 64);
        float f = sqrtf(sq) / (1.0f + sq);
        float4 o = {s.x * f, s.y * f, s.z * f, s.w * f};
        *reinterpret_cast<float4*>(vout + (size_t)(b * L + l) * V + vg * 4) = o;
    }
}

// ---------------------------------------------------------------------------
// K_bc v6: block = (ch of 16 p, b), 512 threads (8 waves). u tile kept in
// REGISTERS (ur[8][2] ushort8/thread); LDS only vsh+bl (20 KB) -> 2 blocks/CU.
// phase 1: all 16 coalesced 1KB u-loads issued early, dot with v -> bl[p][l].
// phase 2: softmax over l per p (each wave 2 p's); b-logit update; optional T.
// phase 3: s-partial from registers, butterfly over pl8 -> sp[b][ch][l][v].
// ---------------------------------------------------------------------------
__global__ __launch_bounds__(512, 4) void k_bc(const ushort* __restrict__ uhat,
                                               const float* __restrict__ vv,
                                               float* __restrict__ bbuf,
                                               float* __restrict__ sp,
                                               float* __restrict__ Tsum,
                                               int add_prev, int do_T) {
    const int ch = blockIdx.x, b = blockIdx.y;
    const int p0 = ch * CHBC;
    const int t = threadIdx.x;
    const int w = t >> 6, lane = t & 63;
    const int pl8 = lane >> 3;   // p-local
    const int vg8 = lane & 7;    // v-octet
    const int l0 = w * 8;

    __shared__ float vsh[L][V];         // 16 KB
    __shared__ float bl[CHBC][L + 1];   // logits, then c in place
    __shared__ float twv[8];

    {
        const float4* vvp = reinterpret_cast<const float4*>(vv + (size_t)b * L * V);
        float4* vshp = reinterpret_cast<float4*>(&vsh[0][0]);
#pragma unroll
        for (int i = 0; i < 2; ++i) vshp[t + i * 512] = vvp[t + i * 512];
    }

    ushort8_t ur[8][2];
    {
        const ushort* ubase = uhat + (((size_t)(b * L + l0)) * P + p0 + pl8) * V + vg8 * 8;
#pragma unroll
        for (int li = 0; li < 8; ++li) {
#pragma unroll
            for (int ph = 0; ph < 2; ++ph)
                ur[li][ph] = *reinterpret_cast<const ushort8_t*>(
                    ubase + ((size_t)li * P + ph * 8) * V);
        }
    }
    __syncthreads();

#pragma unroll
    for (int li = 0; li < 8; ++li) {
        const int l = l0 + li;
        const float4 va = *reinterpret_cast<const float4*>(&vsh[l][vg8 * 8]);
        const float4 vb = *reinterpret_cast<const float4*>(&vsh[l][vg8 * 8 + 4]);
#pragma unroll
        for (int ph = 0; ph < 2; ++ph) {
            float d;
            d = bf2f(ur[li][ph][0]) * va.x;
            d = fmaf(bf2f(ur[li][ph][1]), va.y, d);
            d = fmaf(bf2f(ur[li][ph][2]), va.z, d);
            d = fmaf(bf2f(ur[li][ph][3]), va.w, d);
            d = fmaf(bf2f(ur[li][ph][4]), vb.x, d);
            d = fmaf(bf2f(ur[li][ph][5]), vb.y, d);
            d = fmaf(bf2f(ur[li][ph][6]), vb.z, d);
            d = fmaf(bf2f(ur[li][ph][7]), vb.w, d);
            d += __shfl_xor(d, 1, 64);
            d += __shfl_xor(d, 2, 64);
            d += __shfl_xor(d, 4, 64);
            if (vg8 == 0) bl[ph * 8 + pl8][l] = d;
        }
    }
    __syncthreads();

    float tloc = 0.f;
#pragma unroll
    for (int pi = 0; pi < 2; ++pi) {
        const int pli = w * 2 + pi;
        const int p = p0 + pli;
        float bv = bl[pli][lane];
        float* bp = bbuf + ((size_t)b * P + p) * L;
        if (add_prev) bv += bp[lane];
        bp[lane] = bv;
        float m = wmax64(bv);
        float e = __expf(bv - m);
        float ssum = wsum64(e);
        float cc = e / ssum;
        bl[pli][lane] = cc;
        if (do_T) tloc += cc * __logf(64.0f * (cc + 1e-12f));
    }
    if (do_T) {
        float dsum = wsum64(tloc);
        if (lane == 0) twv[w] = dsum;
    }
    __syncthreads();
    if (do_T && t == 0) {
        float s8 = twv[0] + twv[1] + twv[2] + twv[3] +
                   twv[4] + twv[5] + twv[6] + twv[7];
        atomicAdd(Tsum, s8 * (1.0f / LN64));
    }

    float* spb = sp + (size_t)(b * NCH_BC + ch) * L * V;
#pragma unroll
    for (int li = 0; li < 8; ++li) {
        const int l = l0 + li;
        const float cA = bl[pl8][l];
        const float cB = bl[8 + pl8][l];
        float4 pa, pb;
        pa.x = cA * bf2f(ur[li][0][0]) + cB * bf2f(ur[li][1][0]);
        pa.y = cA * bf2f(ur[li][0][1]) + cB * bf2f(ur[li][1][1]);
        pa.z = cA * bf2f(ur[li][0][2]) + cB * bf2f(ur[li][1][2]);
        pa.w = cA * bf2f(ur[li][0][3]) + cB * bf2f(ur[li][1][3]);
        pb.x = cA * bf2f(ur[li][0][4]) + cB * bf2f(ur[li][1][4]);
        pb.y = cA * bf2f(ur[li][0][5]) + cB * bf2f(ur[li][1][5]);
        pb.z = cA * bf2f(ur[li][0][6]) + cB * bf2f(ur[li][1][6]);
        pb.w = cA * bf2f(ur[li][0][7]) + cB * bf2f(ur[li][1][7]);
#pragma unroll
        for (int m = 8; m <= 32; m <<= 1) {
            pa.x += __shfl_xor(pa.x, m, 64);
            pa.y += __shfl_xor(pa.y, m, 64);
            pa.z += __shfl_xor(pa.z, m, 64);
            pa.w += __shfl_xor(pa.w, m, 64);
            pb.x += __shfl_xor(pb.x, m, 64);
            pb.y += __shfl_xor(pb.y, m, 64);
            pb.z += __shfl_xor(pb.z, m, 64);
            pb.w += __shfl_xor(pb.w, m, 64);
        }
        if (pl8 == 0) {
            *reinterpret_cast<float4*>(spb + (size_t)l * V + vg8 * 8) = pa;
            *reinterpret_cast<float4*>(spb + (size_t)l * V + vg8 * 8 + 4) = pb;
        }
    }
}

// ---------------------------------------------------------------------------
// K_v: chunk-reduce + squash. sp[b][ch][l][v]. grid (L/4, B); wave w -> l.
// ---------------------------------------------------------------------------
__global__ __launch_bounds__(256) void k_v(const float* __restrict__ sp,
                                           float* __restrict__ vout,
                                           float* __restrict__ norms) {
    const int b = blockIdx.y;
    const int w = threadIdx.x >> 6, lane = threadIdx.x & 63;
    const int l = blockIdx.x * 4 + w;
    const float* p = sp + ((size_t)b * NCH_BC * L + l) * V + lane;
    float s = 0.f;
#pragma unroll 8
    for (int ch = 0; ch < NCH_BC; ++ch) s += p[(size_t)ch * L * V];
    float sq = wsum64(s * s);
    float f = sqrtf(sq) / (1.0f + sq);
    vout[((size_t)b * L + l) * V + lane] = s * f;
    if (norms && lane == 0) norms[b * L + l] = sq / (1.0f + sq);
}

// ---------------------------------------------------------------------------
// K_final: T and D. One block, 64 threads (lane = l).
// ---------------------------------------------------------------------------
__global__ void k_final(const float* __restrict__ Tsum,
                        const float* __restrict__ norms,
                        float* __restrict__ out) {
    const int lane = threadIdx.x & 63;
    float n[B];
    float sum = 0.f;
#pragma unroll
    for (int b = 0; b < B; ++b) { n[b] = norms[b * L + lane]; sum += n[b]; }
    const float mean = sum * (1.0f / B);
    float var = 0.f;
#pragma unroll
    for (int b = 0; b < B; ++b) { float d = n[b] - mean; var = fmaf(d, d, var); }
    var *= (1.0f / B);
    float sd = sqrtf(var);
    float D = wmax64(sd);
    if (lane == 0) {
        out[B * L * V] = Tsum[0] * (1.0f / (B * P));
        out[B * L * V + 1] = D;
    }
}

extern "C" void kernel_launch(void* const* d_in, const int* in_sizes, int n_in,
                              void* d_out, int out_size, void* d_ws, size_t ws_size,
                              hipStream_t stream) {
    const float* x = (const float*)d_in[0];   // (B,P,Q)
    const float* W = (const float*)d_in[1];   // (L,P,V,Q)
    float* out = (float*)d_out;               // v (B,L,V) then T, D

    char* ws = (char*)d_ws;
    ushort* uhat = (ushort*)ws;                        // [b][l][p][v] bf16 = 128 MB
    size_t off = (size_t)B * L * P * V * 2;
    float* spbuf = (float*)(ws + off); off += (size_t)B * NCH_BC * L * V * 4;  // 16 MB
    float* vbuf  = (float*)(ws + off); off += (size_t)B * L * V * 4;
    float* bbuf  = (float*)(ws + off); off += (size_t)B * P * L * 4;           // 4 MB [b][p][l]
    float* norms = (float*)(ws + off); off += (size_t)B * L * 4;
    float* Tsum  = (float*)(ws + off); off += 256;

    hipMemsetAsync(Tsum, 0, sizeof(float), stream);

    // u_hat (coalesced staged W reads, store-ack-free vmcnt schedule)
    hipLaunchKernelGGL(k_uhat, dim3(2048), dim3(256), 0, stream, W, x, uhat);
    // iter 0: uniform c -> v0
    hipLaunchKernelGGL(k_s, dim3(L, B), dim3(256), 0, stream, uhat, vbuf);
    // b1 = v0.u ; c1 ; partial s1 (fused, u in registers)
    hipLaunchKernelGGL(k_bc, dim3(NCH_BC, B), dim3(512), 0, stream,
                       uhat, vbuf, bbuf, spbuf, Tsum, 0, 0);
    // v1
    hipLaunchKernelGGL(k_v, dim3(L / 4, B), dim3(256), 0, stream,
                       spbuf, vbuf, (float*)nullptr);
    // b2 = b1 + v1.u ; c2 ; T partials ; partial s2
    hipLaunchKernelGGL(k_bc, dim3(NCH_BC, B), dim3(512), 0, stream,
                       uhat, vbuf, bbuf, spbuf, Tsum, 1, 1);
    // v2 -> out, norms
    hipLaunchKernelGGL(k_v, dim3(L / 4, B), dim3(256), 0, stream,
                       spbuf, out, norms);
    hipLaunchKernelGGL(k_final, dim3(1), dim3(64), 0, stream, Tsum, norms, out);
}